// Round 9
// baseline (183.382 us; speedup 1.0000x reference)
//
#include <hip/hip_runtime.h>

// Problem constants
#define BN   4
#define NN   128
#define INF  256
#define EF   128
#define OUTF 128
#define EPSF 1e-5f
#define NEGF -998244352.0f   // bf16(1e9); matches the bf16-rounded np reference

typedef __attribute__((ext_vector_type(8))) short short8;
typedef __attribute__((ext_vector_type(4))) float f32x4;

#define MFMA16(a, b, c) __builtin_amdgcn_mfma_f32_16x16x32_bf16(a, b, c, 0, 0, 0)

__device__ __forceinline__ unsigned short f2bf(float f) {
    unsigned u = __float_as_uint(f);
    u += 0x7fffu + ((u >> 16) & 1u);
    return (unsigned short)(u >> 16);
}
__device__ __forceinline__ unsigned pack2(float a, float b) {
    return (unsigned)f2bf(a) | ((unsigned)f2bf(b) << 16);
}

// ---- workspace layout (float offsets) ----
constexpr size_t TRI1 = 0;            // B*N*8   tri_1 (masked)  [folded into E1T; kept]
constexpr size_t TRI2 = 4096;
constexpr size_t TRI3 = 8192;
constexpr size_t MSG1 = 12288;        // B*N*128 msg_1 (masked)
constexpr size_t MSG2 = 77824;
constexpr size_t ZWU1 = 143360;
constexpr size_t TRIG = 208896;       // B*8
constexpr size_t MSGG = 209920;       // B*128
constexpr size_t E1T  = 210944;       // B*N*N*8  fp32 [b][j][i][c]  (tri_e1 + tri_1 folded)
constexpr size_t E2T  = 735232;       // B*N*N*8  fp32 [b][k][i][c]
constexpr size_t E3N  = 1259520;      // B*N*N*8  fp32 [b][j][k][c]
constexpr size_t PREPF = 1914880;     // bf16 prepped weights (ushort region, 49152 u16)
constexpr size_t ET_F  = 1939456;     // bf16 e_T [b][j] -> 32KB swizzled LDS image (16MB)

// prep (ushort units), MFMA-fragment order:
// ((ks*8 + t)*64 + lane)*8 + jj == W^T[16t + (lane&15)][ks*32 + (lane>>4)*8 + jj]
// Each ks-slab is 4096 ushorts (8KB); a half-set (2 ks) is 8192 ushorts (16KB).
constexpr int W1T_OFF  = 0;
constexpr int W2T_OFF  = 16384;
constexpr int WMET_OFF = 32768;

// ---- output layout (float offsets): ret, msgs, tri_msgs ----
constexpr size_t O_RET = 0;
constexpr size_t O_MSG = 65536;
constexpr size_t O_TRI = 131072;

__device__ __forceinline__ int detect_int(const void* mask) {
    const unsigned char* m = (const unsigned char*)mask;
    return (m[1] | m[2] | m[3]) == 0 ? 1 : 0;
}
__device__ __forceinline__ bool rdbool(const void* p, size_t idx, int isInt) {
    if (isInt) return ((const int*)p)[idx] != 0;
    return ((const unsigned char*)p)[idx] != 0;
}

// direct global->LDS copy of one 16KB weight HALF-set (r6: no VGPR round
// trip, no spill). Each wave copies 4KB: wave-uniform LDS base + lane*16.
__device__ __forceinline__ void stage_h(const unsigned short* __restrict__ prep, int offU,
                                        unsigned short* Wl, int w, int lane)
{
    const char* g = (const char*)(prep + offU) + w * 4096 + lane * 16;
    char* l = (char*)Wl + w * 4096;   // wave-uniform
    #pragma unroll
    for (int r = 0; r < 4; r++) {
        __builtin_amdgcn_global_load_lds(
            (const __attribute__((address_space(1))) void*)(g + r * 1024),
            (__attribute__((address_space(3))) void*)(l + r * 1024),
            16, 0, 0);
    }
}

// ============================================================
// K1: tri-e projection (0..511) + z proj (512..1023) + graph (1024..1027)
//     + weight prep (1028..1219).  256 thr.
// NEW (r9): tri-e block (b,i) also writes e_T[b][j][i][c] bf16, laid out
// as the XOR-swizzled (byte ^= (i&7)<<4 within the 256B row) LDS image so
// k_main's pair block can global_load_lds it linearly (m173 pattern:
// pre-swizzle the global source, keep LDS dest linear).
// ============================================================
__global__ __launch_bounds__(256, 4) void k_pre(
    const float* __restrict__ z, const float* __restrict__ e, const void* __restrict__ mask,
    const float* __restrict__ Wt1, const float* __restrict__ Wt2, const float* __restrict__ Wt3,
    const float* __restrict__ Wm1, const float* __restrict__ Wm2, const float* __restrict__ WU1,
    const float* __restrict__ g, const float* __restrict__ Wg, const float* __restrict__ Wmg,
    const float* __restrict__ W1, const float* __restrict__ W2, const float* __restrict__ Wme,
    const float* __restrict__ We1, const float* __restrict__ We2, const float* __restrict__ We3,
    float* __restrict__ ws, unsigned short* __restrict__ prep)
{
    int bx = blockIdx.x, tid = threadIdx.x;
    __shared__ __align__(16) unsigned char smem[128 * 136 * 2];

    if (bx < 512) {
        // ---------- tri-e projection: block = one (b,i) ----------
        unsigned short* Ab = (unsigned short*)smem;
        int bi = bx;
        int b = bi >> 7, i = bi & 127;
        int lane = tid & 63, w = tid >> 6, q = lane >> 4, n = lane & 15;
        {
            int half = lane >> 5, c4 = (lane & 31) * 4;
            #pragma unroll
            for (int it = 0; it < 16; it++) {
                int row = 32 * w + 2 * it + half;
                float4 v = *(const float4*)(e + (size_t)bi * 16384 + (size_t)row * 128 + c4);
                unsigned* dst = (unsigned*)&Ab[row * 136 + c4];
                dst[0] = pack2(v.x, v.y);
                dst[1] = pack2(v.z, v.w);
            }
        }
        // t1 row for node i: masked z[b,i,:]@Wt1, per-wave redundant.
        float t1v;
        {
            int c = lane & 7, kk = lane >> 3;   // kk in 0..7, 32-k chunks
            const float* zr = z + (size_t)bi * INF;
            float s = 0.f;
            #pragma unroll
            for (int m = 0; m < 32; m++) s = fmaf(zr[kk * 32 + m], Wt1[(kk * 32 + m) * 8 + c], s);
            s += __shfl_xor(s, 8, 64);
            s += __shfl_xor(s, 16, 64);
            s += __shfl_xor(s, 32, 64);
            int isInt = detect_int(mask);
            t1v = rdbool(mask, bi, isInt) ? s : 0.f;
        }
        // gather packed-We B fragments (cols: We1|We2|We3|0), L1-hot 4KB arrays
        short8 bfrag[4][2];
        {
            #pragma unroll
            for (int t = 0; t < 2; t++) {
                int col = 16 * t + n;
                const float* Wsel = (col < 8) ? We1 : (col < 16 ? We2 : We3);
                int csel = col & 7;
                float mval = (col < 24) ? 1.f : 0.f;
                #pragma unroll
                for (int ks = 0; ks < 4; ks++) {
                    union { short8 s; unsigned short u[8]; } tmp;
                    #pragma unroll
                    for (int jj = 0; jj < 8; jj++) {
                        int k = ks * 32 + q * 8 + jj;
                        tmp.u[jj] = f2bf(Wsel[k * 8 + csel] * mval);
                    }
                    bfrag[ks][t] = tmp.s;
                }
            }
        }
        __builtin_amdgcn_wave_barrier();

        f32x4 ac2[2][2];
        #pragma unroll
        for (int rt = 0; rt < 2; rt++)
            #pragma unroll
            for (int t = 0; t < 2; t++) ac2[rt][t] = 0.f;
        #pragma unroll
        for (int ks = 0; ks < 4; ks++) {
            int k0 = ks * 32 + q * 8;
            short8 a0 = *(const short8*)&Ab[(32 * w + n) * 136 + k0];
            short8 a1 = *(const short8*)&Ab[(32 * w + 16 + n) * 136 + k0];
            #pragma unroll
            for (int t = 0; t < 2; t++) {
                ac2[0][t] = MFMA16(a0, bfrag[ks][t], ac2[0][t]);
                ac2[1][t] = MFMA16(a1, bfrag[ks][t], ac2[1][t]);
            }
        }
        #pragma unroll
        for (int rt = 0; rt < 2; rt++)
            #pragma unroll
            for (int reg = 0; reg < 4; reg++) {
                int row = 32 * w + 16 * rt + 4 * q + reg;
                float v0 = ac2[rt][0][reg];
                if (n < 8) ws[E1T + ((size_t)(b * 128 + row) * 128 + i) * 8 + n] = v0 + t1v;
                else       ws[E2T + ((size_t)(b * 128 + row) * 128 + i) * 8 + (n - 8)] = v0;
                if (n < 8) ws[E3N + ((size_t)bi * 128 + row) * 8 + n] = ac2[rt][1][reg];
            }
        // ---- e_T write: all 128 Ab rows -> swizzled bf16 global image ----
        __syncthreads();   // Ab rows of all waves now readable
        {
            unsigned short* eT = (unsigned short*)(ws + ET_F);
            int jj = tid >> 1, hf = tid & 1;
            int xr = (i & 7) << 4;
            char* dstb = (char*)(eT + (size_t)(b * 128 + jj) * 16384) + i * 256;
            const char* srcb = (const char*)&Ab[jj * 136 + hf * 64];
            #pragma unroll
            for (int m = 0; m < 8; m++) {
                int off = (hf * 128 + m * 16) ^ xr;
                *(uint4*)(dstb + off) = *(const uint4*)(srcb + m * 16);
            }
        }
        return;
    }
    if (bx < 1024) {
        // ---------- z-row projections (2-way split accumulators for ILP) ----------
        int bn = bx - 512;
        int isInt = detect_int(mask);
        float* zr = (float*)smem;
        zr[tid] = z[(size_t)bn * INF + tid];
        __syncthreads();
        float mk = rdbool(mask, bn, isInt) ? 1.f : 0.f;
        for (int idx = tid; idx < 408; idx += 256) {
            const float* W; int c; size_t dst; int width; bool msk;
            if (idx < 8)        { W = Wt1; c = idx;       dst = TRI1 + (size_t)bn * 8;   width = 8;   msk = true;  }
            else if (idx < 16)  { W = Wt2; c = idx - 8;   dst = TRI2 + (size_t)bn * 8;   width = 8;   msk = true;  }
            else if (idx < 24)  { W = Wt3; c = idx - 16;  dst = TRI3 + (size_t)bn * 8;   width = 8;   msk = true;  }
            else if (idx < 152) { W = Wm1; c = idx - 24;  dst = MSG1 + (size_t)bn * 128; width = 128; msk = true;  }
            else if (idx < 280) { W = Wm2; c = idx - 152; dst = MSG2 + (size_t)bn * 128; width = 128; msk = true;  }
            else                { W = WU1; c = idx - 280; dst = ZWU1 + (size_t)bn * 128; width = 128; msk = false; }
            float a0 = 0.f, a1 = 0.f;
            #pragma unroll 8
            for (int k = 0; k < INF; k += 2) {
                a0 += zr[k] * W[k * width + c];
                a1 += zr[k + 1] * W[(k + 1) * width + c];
            }
            float acc = a0 + a1;
            ws[dst + c] = msk ? acc * mk : acc;
        }
        return;
    }
    if (bx < 1028) {
        // ---------- graph_fts projections ----------
        int b = bx - 1024;
        float* gr = (float*)smem;
        if (tid < 128) gr[tid] = g[b * 128 + tid];
        __syncthreads();
        if (tid < 8) {
            float a = 0.f;
            for (int k = 0; k < 128; k++) a += gr[k] * Wg[k * 8 + tid];
            ws[TRIG + b * 8 + tid] = a;
        } else if (tid >= 128) {
            int c = tid - 128;
            float a = 0.f;
            for (int k = 0; k < 128; k++) a += gr[k] * Wmg[k * 128 + c];
            ws[MSGG + b * 128 + c] = a;
        }
        return;
    }
    // ---------- weight prep (fragment-order), W1/W2/Wme only ----------
    {
        int idx = (bx - 1028) * 256 + tid;   // < 49152
        const float* W = (idx < 16384) ? W1 : (idx < 32768 ? W2 : Wme);
        int local = idx & 16383;
        int f = local >> 3, jj = local & 7;
        int lane = f & 63, fg = f >> 6;
        int t = fg & 7, ks = fg >> 3;
        int n = lane & 15, q = lane >> 4;
        int row = 16 * t + n;
        int k = ks * 32 + q * 8 + jj;
        prep[idx] = f2bf(W[k * 128 + row]);
    }
}

// ============================================================
// K2: bx<256 triplet pooling, bx>=256 pair-MLP (32 rows/wave) with fused
// final LN. grid 768, block 256, LDS 51,200B -> 3 blocks/CU.
// Pair A-matrix staged from pre-packed e_T via global_load_lds (8/wave),
// XOR-swizzled image: A-read at byte row*256 + (2k ^ ((row&7)<<4)) keeps
// the free 2-way bank aliasing of the old 136-stride layout.
// ============================================================
#define PAIR_GEMM_H(HS) do {                                                   \
    int xa = (n & 7) << 4;                                                     \
    _Pragma("unroll")                                                          \
    for (int ls = 0; ls < 2; ls++) {                                           \
        int kb2 = ((2 * (HS) + ls) * 32 + q * 8) * 2;                          \
        short8 a0 = *(const short8*)((const char*)Ab + (32 * w + n) * 256 + (kb2 ^ xa));      \
        short8 a1 = *(const short8*)((const char*)Ab + (32 * w + 16 + n) * 256 + (kb2 ^ xa)); \
        _Pragma("unroll")                                                      \
        for (int t = 0; t < 8; t++) {                                          \
            short8 bt = *(const short8*)&Wl[((ls * 8 + t) * 64 + lane) * 8];   \
            acc[0][t] = MFMA16(a0, bt, acc[0][t]);                             \
            acc[1][t] = MFMA16(a1, bt, acc[1][t]);                             \
        }                                                                      \
    }                                                                          \
} while (0)

__global__ __launch_bounds__(256, 3) void k_main(
    const void* __restrict__ mask, const void* __restrict__ adj,
    const float* __restrict__ ln1s, const float* __restrict__ ln1o,
    const float* __restrict__ ln2s, const float* __restrict__ ln2o,
    const unsigned short* __restrict__ prep, const float* __restrict__ WU3,
    const float* __restrict__ WU2, const float* __restrict__ lnfs, const float* __restrict__ lnfo,
    float* __restrict__ ws, float* __restrict__ out)
{
    int bx = blockIdx.x, tid = threadIdx.x;
    __shared__ __align__(16) unsigned char smem[51200];
    int lane = tid & 63, w = tid >> 6, q = lane >> 4, n = lane & 15;
    int isInt = detect_int(mask);

    if (bx < 256) {
        // ================= triplet max-plus pooling =================
        int g = bx;
        int j0 = ((g >> 3) & 7) * 16, k0 = (g & 7) * 16, b = g >> 6;
        int wi = w >> 1, wc = w & 1;          // i-half, channel-half
        int tj = lane >> 3, tk = lane & 7;    // 8x8 lanes; outputs (tj,tj+8)x(tk,tk+8)
        int col4 = (tid & 31) * 4, rowgrp = tid >> 5;

        int lenb;
        {
            unsigned long long m0 = __ballot(rdbool(mask, (size_t)b * 128 + lane, isInt));
            unsigned long long m1 = __ballot(rdbool(mask, (size_t)b * 128 + 64 + lane, isInt));
            lenb = __popcll(m0) + __popcll(m1);
        }
        bool needU = (j0 + 15 >= lenb) && (k0 + 15 >= lenb);

        // wave-private staging: P[16][8ii][4c]+pad and Q, stride 36 words
        float* Pb = (float*)smem + w * 1152;
        float* Qb = Pb + 576;

        f32x4 aM[2][2];
        #pragma unroll
        for (int jj = 0; jj < 2; jj++)
            #pragma unroll
            for (int kk = 0; kk < 2; kk++) aM[jj][kk] = NEGF;

        if (!needU) {
            // fast path: every output has mj|mk true -> max over ALL i, one acc set
            for (int ch = 0; ch < 8; ch++) {
                int ibase = wi * 64 + ch * 8;
                #pragma unroll
                for (int r = 0; r < 2; r++) {
                    int f = r * 64 + lane;
                    int jr = f >> 3, ii = f & 7;
                    f32x4 pv = *(const f32x4*)(ws + E1T + (size_t)(b * 128 + j0 + jr) * 1024 + (ibase + ii) * 8 + wc * 4);
                    f32x4 qv = *(const f32x4*)(ws + E2T + (size_t)(b * 128 + k0 + jr) * 1024 + (ibase + ii) * 8 + wc * 4);
                    *(f32x4*)(Pb + jr * 36 + ii * 4) = pv;
                    *(f32x4*)(Qb + jr * 36 + ii * 4) = qv;
                }
                __builtin_amdgcn_wave_barrier();
                #pragma unroll
                for (int ii = 0; ii < 8; ii++) {
                    f32x4 p0 = *(const f32x4*)(Pb + tj * 36 + ii * 4);
                    f32x4 p1 = *(const f32x4*)(Pb + (tj + 8) * 36 + ii * 4);
                    f32x4 q0 = *(const f32x4*)(Qb + tk * 36 + ii * 4);
                    f32x4 q1 = *(const f32x4*)(Qb + (tk + 8) * 36 + ii * 4);
                    aM[0][0] = __builtin_elementwise_max(aM[0][0], p0 + q0);
                    aM[0][1] = __builtin_elementwise_max(aM[0][1], p0 + q1);
                    aM[1][0] = __builtin_elementwise_max(aM[1][0], p1 + q0);
                    aM[1][1] = __builtin_elementwise_max(aM[1][1], p1 + q1);
                }
            }
        } else {
            f32x4 aU[2][2];
            #pragma unroll
            for (int jj = 0; jj < 2; jj++)
                #pragma unroll
                for (int kk = 0; kk < 2; kk++) aU[jj][kk] = NEGF;
            unsigned long long mball = __ballot(rdbool(mask, (size_t)b * 128 + wi * 64 + lane, isInt));
            for (int ch = 0; ch < 8; ch++) {
                int ibase = wi * 64 + ch * 8;
                #pragma unroll
                for (int r = 0; r < 2; r++) {
                    int f = r * 64 + lane;
                    int jr = f >> 3, ii = f & 7;
                    f32x4 pv = *(const f32x4*)(ws + E1T + (size_t)(b * 128 + j0 + jr) * 1024 + (ibase + ii) * 8 + wc * 4);
                    f32x4 qv = *(const f32x4*)(ws + E2T + (size_t)(b * 128 + k0 + jr) * 1024 + (ibase + ii) * 8 + wc * 4);
                    *(f32x4*)(Pb + jr * 36 + ii * 4) = pv;
                    *(f32x4*)(Qb + jr * 36 + ii * 4) = qv;
                }
                __builtin_amdgcn_wave_barrier();
                #pragma unroll
                for (int ii = 0; ii < 8; ii++) {
                    f32x4 p0 = *(const f32x4*)(Pb + tj * 36 + ii * 4);
                    f32x4 p1 = *(const f32x4*)(Pb + (tj + 8) * 36 + ii * 4);
                    f32x4 q0 = *(const f32x4*)(Qb + tk * 36 + ii * 4);
                    f32x4 q1 = *(const f32x4*)(Qb + (tk + 8) * 36 + ii * 4);
                    f32x4 v00 = p0 + q0, v01 = p0 + q1, v10 = p1 + q0, v11 = p1 + q1;
                    if ((mball >> (ch * 8 + ii)) & 1) {
                        aM[0][0] = __builtin_elementwise_max(aM[0][0], v00);
                        aM[0][1] = __builtin_elementwise_max(aM[0][1], v01);
                        aM[1][0] = __builtin_elementwise_max(aM[1][0], v10);
                        aM[1][1] = __builtin_elementwise_max(aM[1][1], v11);
                    } else {
                        aU[0][0] = __builtin_elementwise_max(aU[0][0], v00);
                        aU[0][1] = __builtin_elementwise_max(aU[0][1], v01);
                        aU[1][0] = __builtin_elementwise_max(aU[1][0], v10);
                        aU[1][1] = __builtin_elementwise_max(aU[1][1], v11);
                    }
                }
            }
            // outputs with mj|mk include unmasked-i contributions too
            bool mj[2], mk2[2];
            mj[0]  = (j0 + tj)     < lenb;
            mj[1]  = (j0 + tj + 8) < lenb;
            mk2[0] = (k0 + tk)     < lenb;
            mk2[1] = (k0 + tk + 8) < lenb;
            #pragma unroll
            for (int jj = 0; jj < 2; jj++)
                #pragma unroll
                for (int kk = 0; kk < 2; kk++)
                    if (mj[jj] | mk2[kk])
                        aM[jj][kk] = __builtin_elementwise_max(aM[jj][kk], aU[jj][kk]);
        }
        __syncthreads();   // all staging reads done; alias staging region as 'pooled'
        float* pooled = (float*)smem;   // [8][260] c-major
        float4 wvr[8];
        #pragma unroll
        for (int c = 0; c < 8; c++) wvr[c] = *(const float4*)(WU3 + c * 128 + col4);

        if (wi == 0) {
            #pragma unroll
            for (int jj = 0; jj < 2; jj++)
                #pragma unroll
                for (int kk = 0; kk < 2; kk++) {
                    int p = (tj + 8 * jj) * 16 + (tk + 8 * kk);
                    #pragma unroll
                    for (int cc = 0; cc < 4; cc++)
                        pooled[(wc * 4 + cc) * 260 + p] = aM[jj][kk][cc];
                }
        }
        __syncthreads();
        if (wi == 1) {
            const float* tg = ws + TRIG + (size_t)b * 8 + wc * 4;
            #pragma unroll
            for (int jj = 0; jj < 2; jj++)
                #pragma unroll
                for (int kk = 0; kk < 2; kk++) {
                    int jv = j0 + tj + 8 * jj, kv = k0 + tk + 8 * kk;
                    const float* t2 = ws + TRI2 + (size_t)(b * 128 + jv) * 8 + wc * 4;
                    const float* t3 = ws + TRI3 + (size_t)(b * 128 + kv) * 8 + wc * 4;
                    const float* e3 = ws + E3N + ((size_t)(b * 128 + jv) * 128 + kv) * 8 + wc * 4;
                    int p = (tj + 8 * jj) * 16 + (tk + 8 * kk);
                    #pragma unroll
                    for (int cc = 0; cc < 4; cc++) {
                        int idx = (wc * 4 + cc) * 260 + p;
                        pooled[idx] = fmaxf(pooled[idx], aM[jj][kk][cc]) + t2[cc] + t3[cc] + e3[cc] + tg[cc];
                    }
                }
        }
        __syncthreads();
        // epilogue: relu(pooled @ WU3); pooled reads broadcast, no LDS weights
        #pragma unroll
        for (int pass = 0; pass < 32; pass++) {
            int p = pass * 8 + rowgrp;
            float4 s = { 0.f, 0.f, 0.f, 0.f };
            #pragma unroll
            for (int c = 0; c < 8; c++) {
                float pv = pooled[c * 260 + p];
                s.x += pv * wvr[c].x; s.y += pv * wvr[c].y;
                s.z += pv * wvr[c].z; s.w += pv * wvr[c].w;
            }
            s.x = fmaxf(s.x, 0.f); s.y = fmaxf(s.y, 0.f);
            s.z = fmaxf(s.z, 0.f); s.w = fmaxf(s.w, 0.f);
            int pj = p >> 4, pk = p & 15;
            *(float4*)(out + O_TRI + ((size_t)(b * 128 + j0 + pj) * 128 + (k0 + pk)) * 128 + col4) = s;
        }
        return;
    }

    // ================= pair MLP: block = one (b,j), 32 rows/wave =================
    unsigned short* Ab = (unsigned short*)smem;                       // [128][128] bf16 swizzled, 32768B
    float* pw = (float*)(smem + 32768);                               // [4][128]   2048B
    unsigned short* Wl = (unsigned short*)(smem + 34816);             // [8192]    16384B (one half-set)
    // fused final-LN scratch aliases Wl (safe: written only after the last
    // barrier that retires Wl reads; dead blocks never stage Wl)
    float* mrowL = (float*)(smem + 34816);    // [128]
    float* partL = mrowL + 128;               // [256]
    float* redL  = partL + 256;               // [4]
    int bj = bx - 256;
    int b = bj >> 7, j = bj & 127;

    int lenb;
    {
        unsigned long long m0 = __ballot(rdbool(mask, (size_t)b * 128 + lane, isInt));
        unsigned long long m1 = __ballot(rdbool(mask, (size_t)b * 128 + 64 + lane, isInt));
        lenb = __popcll(m0) + __popcll(m1);
    }
    bool live = (j < lenb);   // block-uniform

    if (live) {
        bool waveActive = (32 * w) < lenb;

        stage_h(prep, WMET_OFF, Wl, w, lane);   // Wme.h0 in flight
        if (waveActive) {
            // A-matrix: 8 async global->LDS per wave from pre-packed e_T
            const char* gA = (const char*)((const unsigned short*)(ws + ET_F)
                              + (size_t)(b * 128 + j) * 16384) + w * 8192 + lane * 16;
            char* lA = (char*)Ab + w * 8192;    // wave-uniform (wave w = rows 32w..32w+31)
            #pragma unroll
            for (int r = 0; r < 8; r++) {
                __builtin_amdgcn_global_load_lds(
                    (const __attribute__((address_space(1))) void*)(gA + r * 1024),
                    (__attribute__((address_space(3))) void*)(lA + r * 1024),
                    16, 0, 0);
            }
        }
        __syncthreads();                        // drains vmcnt: Wme.h0 + A ready

        float colmax[8];
        #pragma unroll
        for (int t = 0; t < 8; t++) colmax[t] = NEGF;
        float adjm[2][4];
        f32x4 acc[2][8];

        // ---- GEMM1: X @ Wme (half-staged) ----
        #pragma unroll
        for (int rt = 0; rt < 2; rt++)
            #pragma unroll
            for (int t = 0; t < 8; t++) acc[rt][t] = 0.f;
        if (waveActive) PAIR_GEMM_H(0);
        __syncthreads();                        // done reading h0
        stage_h(prep, WMET_OFF + 8192, Wl, w, lane);
        __syncthreads();                        // h1 ready
        if (waveActive) PAIR_GEMM_H(1);
        __syncthreads();                        // done reading h1
        stage_h(prep, W1T_OFF, Wl, w, lane);    // W1.h0 hides under epilogue1

        if (waveActive) {
            float msum[8];
            #pragma unroll
            for (int t = 0; t < 8; t++)
                msum[t] = ws[MSG1 + (size_t)bj * 128 + 16 * t + n] + ws[MSGG + (size_t)b * 128 + 16 * t + n];
            float rs[2][4], rss[2][4];
            #pragma unroll
            for (int rt = 0; rt < 2; rt++)
                #pragma unroll
                for (int reg = 0; reg < 4; reg++) {
                    int row = 32 * w + 16 * rt + 4 * q + reg;
                    bool av = rdbool(adj, ((size_t)b * 128 + row) * 128 + j, isInt);
                    adjm[rt][reg] = av ? 1.f : 0.f;
                    float s = 0.f, ssq = 0.f;
                    #pragma unroll
                    for (int t = 0; t < 8; t++) {
                        float v = acc[rt][t][reg] * adjm[rt][reg]
                                + ws[MSG2 + ((size_t)b * 128 + row) * 128 + 16 * t + n] + msum[t];
                        acc[rt][t][reg] = v;
                        s += v; ssq += v * v;
                    }
                    rs[rt][reg] = s; rss[rt][reg] = ssq;
                }
            #pragma unroll
            for (int d = 1; d < 16; d <<= 1) {
                #pragma unroll
                for (int rt = 0; rt < 2; rt++)
                    #pragma unroll
                    for (int reg = 0; reg < 4; reg++) {
                        rs[rt][reg]  += __shfl_xor(rs[rt][reg], d, 64);
                        rss[rt][reg] += __shfl_xor(rss[rt][reg], d, 64);
                    }
            }
            float s1v[8], o1v[8];
            #pragma unroll
            for (int t = 0; t < 8; t++) { s1v[t] = ln1s[16 * t + n]; o1v[t] = ln1o[16 * t + n]; }
            #pragma unroll
            for (int rt = 0; rt < 2; rt++)
                #pragma unroll
                for (int reg = 0; reg < 4; reg++) {
                    float mu = rs[rt][reg] * (1.f / 128);
                    float inv = rsqrtf(rss[rt][reg] * (1.f / 128) - mu * mu + EPSF);
                    int row = 32 * w + 16 * rt + 4 * q + reg;
                    int xw = (row & 7) << 4;
                    #pragma unroll
                    for (int t = 0; t < 8; t++) {
                        float v = fmaxf(s1v[t] * inv * (acc[rt][t][reg] - mu) + o1v[t], 0.f);
                        *(unsigned short*)((char*)Ab + row * 256 + ((2 * (16 * t + n)) ^ xw)) = f2bf(v);
                    }
                }
        }
        __syncthreads();                        // drains vmcnt: W1.h0 ready

        // ---- GEMM2: relu(LN1) @ W1 (half-staged) ----
        #pragma unroll
        for (int rt = 0; rt < 2; rt++)
            #pragma unroll
            for (int t = 0; t < 8; t++) acc[rt][t] = 0.f;
        if (waveActive) PAIR_GEMM_H(0);
        __syncthreads();
        stage_h(prep, W1T_OFF + 8192, Wl, w, lane);
        __syncthreads();
        if (waveActive) PAIR_GEMM_H(1);
        __syncthreads();
        stage_h(prep, W2T_OFF, Wl, w, lane);    // W2.h0 hides under epilogue2

        if (waveActive) {
            float rs[2][4], rss[2][4];
            #pragma unroll
            for (int rt = 0; rt < 2; rt++)
                #pragma unroll
                for (int reg = 0; reg < 4; reg++) {
                    float s = 0.f, ssq = 0.f;
                    #pragma unroll
                    for (int t = 0; t < 8; t++) { float v = acc[rt][t][reg]; s += v; ssq += v * v; }
                    rs[rt][reg] = s; rss[rt][reg] = ssq;
                }
            #pragma unroll
            for (int d = 1; d < 16; d <<= 1) {
                #pragma unroll
                for (int rt = 0; rt < 2; rt++)
                    #pragma unroll
                    for (int reg = 0; reg < 4; reg++) {
                        rs[rt][reg]  += __shfl_xor(rs[rt][reg], d, 64);
                        rss[rt][reg] += __shfl_xor(rss[rt][reg], d, 64);
                    }
            }
            float s2v[8], o2v[8];
            #pragma unroll
            for (int t = 0; t < 8; t++) { s2v[t] = ln2s[16 * t + n]; o2v[t] = ln2o[16 * t + n]; }
            #pragma unroll
            for (int rt = 0; rt < 2; rt++)
                #pragma unroll
                for (int reg = 0; reg < 4; reg++) {
                    float mu = rs[rt][reg] * (1.f / 128);
                    float inv = rsqrtf(rss[rt][reg] * (1.f / 128) - mu * mu + EPSF);
                    int row = 32 * w + 16 * rt + 4 * q + reg;
                    int xw = (row & 7) << 4;
                    #pragma unroll
                    for (int t = 0; t < 8; t++) {
                        float v = fmaxf(s2v[t] * inv * (acc[rt][t][reg] - mu) + o2v[t], 0.f);
                        *(unsigned short*)((char*)Ab + row * 256 + ((2 * (16 * t + n)) ^ xw)) = f2bf(v);
                    }
                }
        }
        __syncthreads();                        // drains vmcnt: W2.h0 ready

        // ---- GEMM3: relu(LN2) @ W2 (half-staged) ----
        #pragma unroll
        for (int rt = 0; rt < 2; rt++)
            #pragma unroll
            for (int t = 0; t < 8; t++) acc[rt][t] = 0.f;
        if (waveActive) PAIR_GEMM_H(0);
        __syncthreads();
        stage_h(prep, W2T_OFF + 8192, Wl, w, lane);
        __syncthreads();
        if (waveActive) {
            PAIR_GEMM_H(1);
            #pragma unroll
            for (int rt = 0; rt < 2; rt++)
                #pragma unroll
                for (int reg = 0; reg < 4; reg++) {
                    if (adjm[rt][reg] > 0.f) {
                        #pragma unroll
                        for (int t = 0; t < 8; t++) colmax[t] = fmaxf(colmax[t], acc[rt][t][reg]);
                    }
                }
        }
        #pragma unroll
        for (int t = 0; t < 8; t++) {
            colmax[t] = fmaxf(colmax[t], __shfl_xor(colmax[t], 16, 64));
            colmax[t] = fmaxf(colmax[t], __shfl_xor(colmax[t], 32, 64));
        }
        if (lane < 16) {
            #pragma unroll
            for (int t = 0; t < 8; t++) pw[w * 128 + 16 * t + lane] = colmax[t];
        }
        __syncthreads();                        // last Wl reads retired; mrowL may alias now
        if (tid < 128) {
            float mx = fmaxf(fmaxf(pw[tid], pw[128 + tid]), fmaxf(pw[256 + tid], pw[384 + tid]));
            mrowL[tid] = mx;
            out[O_MSG + (size_t)bj * 128 + tid] = mx;
        }
    } else {
        // dead column: msgs row = NEGF exactly as the all-false colmax path
        if (tid < 128) {
            mrowL[tid] = NEGF;
            out[O_MSG + (size_t)bj * 128 + tid] = NEGF;
        }
    }
    __syncthreads();

    // ---- fused final LN (was K3): ret = LN(z@WU1 + msgs@WU2) ----
    {
        int c = tid & 127, hf = tid >> 7;
        int kb = hf * 64;
        float a0 = 0.f, a1 = 0.f;
        #pragma unroll 8
        for (int k = 0; k < 64; k += 2) {
            a0 = fmaf(mrowL[kb + k],     WU2[(size_t)(kb + k) * 128 + c],     a0);
            a1 = fmaf(mrowL[kb + k + 1], WU2[(size_t)(kb + k + 1) * 128 + c], a1);
        }
        partL[hf * 128 + c] = a0 + a1;
        __syncthreads();
        float y = ws[ZWU1 + (size_t)bj * 128 + c] + partL[c] + partL[128 + c];
        float s = y, ss = y * y;
        #pragma unroll
        for (int d = 1; d < 64; d <<= 1) { s += __shfl_xor(s, d, 64); ss += __shfl_xor(ss, d, 64); }
        if (tid == 0 || tid == 64) { redL[(tid >> 6) * 2] = s; redL[(tid >> 6) * 2 + 1] = ss; }
        __syncthreads();
        float S = redL[0] + redL[2], SS = redL[1] + redL[3];
        float m_ = S * (1.f / 128), v_ = SS * (1.f / 128) - m_ * m_;
        float r = rsqrtf(v_ + EPSF);
        if (tid < 128) out[O_RET + (size_t)bj * 128 + c] = lnfs[c] * r * (y - m_) + lnfo[c];
    }
}

// ============================================================
extern "C" void kernel_launch(void* const* d_in, const int* in_sizes, int n_in,
                              void* d_out, int out_size, void* d_ws, size_t ws_size,
                              hipStream_t stream)
{
    const float* z    = (const float*)d_in[0];
    const float* e    = (const float*)d_in[1];
    const float* gf   = (const float*)d_in[2];
    const void*  mask = d_in[3];
    const void*  adj  = d_in[4];
    const float* Wt1 = (const float*)d_in[5];
    const float* Wt2 = (const float*)d_in[6];
    const float* Wt3 = (const float*)d_in[7];
    const float* We1 = (const float*)d_in[8];
    const float* We2 = (const float*)d_in[9];
    const float* We3 = (const float*)d_in[10];
    const float* Wg  = (const float*)d_in[11];
    const float* Wm1 = (const float*)d_in[12];
    const float* Wm2 = (const float*)d_in[13];
    const float* Wme = (const float*)d_in[14];
    const float* Wmg = (const float*)d_in[15];
    const float* ln1s = (const float*)d_in[16];
    const float* ln1o = (const float*)d_in[17];
    const float* W1   = (const float*)d_in[18];
    const float* ln2s = (const float*)d_in[19];
    const float* ln2o = (const float*)d_in[20];
    const float* W2   = (const float*)d_in[21];
    const float* WU1  = (const float*)d_in[22];
    const float* WU2  = (const float*)d_in[23];
    const float* WU3  = (const float*)d_in[24];
    const float* lnfs = (const float*)d_in[25];
    const float* lnfo = (const float*)d_in[26];
    float* out = (float*)d_out;
    float* ws  = (float*)d_ws;
    unsigned short* prep = (unsigned short*)(ws + PREPF);

    hipLaunchKernelGGL(k_pre, dim3(1220), dim3(256), 0, stream,
                       z, e, mask, Wt1, Wt2, Wt3, Wm1, Wm2, WU1, gf, Wg, Wmg,
                       W1, W2, Wme, We1, We2, We3, ws, prep);
    hipLaunchKernelGGL(k_main, dim3(768), dim3(256), 0, stream,
                       mask, adj, ln1s, ln1o, ln2s, ln2o, prep, WU3,
                       WU2, lnfs, lnfo, ws, out);
}

// Round 10
// 181.706 us; speedup vs baseline: 1.0092x; 1.0092x over previous
//
#include <hip/hip_runtime.h>

// Problem constants
#define BN   4
#define NN   128
#define INF  256
#define EF   128
#define OUTF 128
#define EPSF 1e-5f
#define NEGF -998244352.0f   // bf16(1e9); matches the bf16-rounded np reference

typedef __attribute__((ext_vector_type(8))) short short8;
typedef __attribute__((ext_vector_type(4))) float f32x4;

#define MFMA16(a, b, c) __builtin_amdgcn_mfma_f32_16x16x32_bf16(a, b, c, 0, 0, 0)

__device__ __forceinline__ unsigned short f2bf(float f) {
    unsigned u = __float_as_uint(f);
    u += 0x7fffu + ((u >> 16) & 1u);
    return (unsigned short)(u >> 16);
}
__device__ __forceinline__ unsigned pack2(float a, float b) {
    return (unsigned)f2bf(a) | ((unsigned)f2bf(b) << 16);
}

// ---- workspace layout (float offsets) ----
constexpr size_t TRI1 = 0;            // B*N*8   tri_1 (masked)  [folded into E1T; kept]
constexpr size_t TRI2 = 4096;
constexpr size_t TRI3 = 8192;
constexpr size_t MSG1 = 12288;        // B*N*128 msg_1 (masked)
constexpr size_t MSG2 = 77824;
constexpr size_t ZWU1 = 143360;
constexpr size_t TRIG = 208896;       // B*8
constexpr size_t MSGG = 209920;       // B*128
constexpr size_t E1T  = 210944;       // B*N*N*8  fp32 [b][j][i][c]  (tri_e1 + tri_1 folded)
constexpr size_t E2T  = 735232;       // B*N*N*8  fp32 [b][k][i][c]
constexpr size_t E3N  = 1259520;      // B*N*N*8  fp32 [b][j][k][c]
constexpr size_t PREPF = 1914880;     // bf16 prepped weights (ushort region)

// prep (ushort units), MFMA-fragment order:
// ((ks*8 + t)*64 + lane)*8 + jj == W^T[16t + (lane&15)][ks*32 + (lane>>4)*8 + jj]
// Each ks-slab is 4096 ushorts (8KB).
constexpr int W1T_OFF  = 0;
constexpr int W2T_OFF  = 16384;
constexpr int WMET_OFF = 32768;

// ---- output layout (float offsets): ret, msgs, tri_msgs ----
constexpr size_t O_RET = 0;
constexpr size_t O_MSG = 65536;
constexpr size_t O_TRI = 131072;

__device__ __forceinline__ int detect_int(const void* mask) {
    const unsigned char* m = (const unsigned char*)mask;
    return (m[1] | m[2] | m[3]) == 0 ? 1 : 0;
}
__device__ __forceinline__ bool rdbool(const void* p, size_t idx, int isInt) {
    if (isInt) return ((const int*)p)[idx] != 0;
    return ((const unsigned char*)p)[idx] != 0;
}

// direct global->LDS copy of one 8KB weight SLAB (one ks). Each wave
// copies 2KB: wave-uniform LDS base + lane*16. No VGPR round trip.
__device__ __forceinline__ void stage_q(const unsigned short* __restrict__ prep, int offU,
                                        unsigned short* Wl, int w, int lane)
{
    const char* g = (const char*)(prep + offU) + w * 2048 + lane * 16;
    char* l = (char*)Wl + w * 2048;   // wave-uniform
    #pragma unroll
    for (int r = 0; r < 2; r++) {
        __builtin_amdgcn_global_load_lds(
            (const __attribute__((address_space(1))) void*)(g + r * 1024),
            (__attribute__((address_space(3))) void*)(l + r * 1024),
            16, 0, 0);
    }
}

// ============================================================
// K1: tri-e projection (0..511) + z proj (512..1023) + graph (1024..1027)
//     + weight prep (1028..1219).  256 thr.  (r8 structure, unchanged.)
// ============================================================
__global__ __launch_bounds__(256, 4) void k_pre(
    const float* __restrict__ z, const float* __restrict__ e, const void* __restrict__ mask,
    const float* __restrict__ Wt1, const float* __restrict__ Wt2, const float* __restrict__ Wt3,
    const float* __restrict__ Wm1, const float* __restrict__ Wm2, const float* __restrict__ WU1,
    const float* __restrict__ g, const float* __restrict__ Wg, const float* __restrict__ Wmg,
    const float* __restrict__ W1, const float* __restrict__ W2, const float* __restrict__ Wme,
    const float* __restrict__ We1, const float* __restrict__ We2, const float* __restrict__ We3,
    float* __restrict__ ws, unsigned short* __restrict__ prep)
{
    int bx = blockIdx.x, tid = threadIdx.x;
    __shared__ __align__(16) unsigned char smem[128 * 136 * 2];

    if (bx < 512) {
        // ---------- tri-e projection: block = one (b,i) ----------
        unsigned short* Ab = (unsigned short*)smem;
        int bi = bx;
        int b = bi >> 7, i = bi & 127;
        int lane = tid & 63, w = tid >> 6, q = lane >> 4, n = lane & 15;
        {
            int half = lane >> 5, c4 = (lane & 31) * 4;
            #pragma unroll
            for (int it = 0; it < 16; it++) {
                int row = 32 * w + 2 * it + half;
                float4 v = *(const float4*)(e + (size_t)bi * 16384 + (size_t)row * 128 + c4);
                unsigned* dst = (unsigned*)&Ab[row * 136 + c4];
                dst[0] = pack2(v.x, v.y);
                dst[1] = pack2(v.z, v.w);
            }
        }
        // t1 row for node i: masked z[b,i,:]@Wt1, per-wave redundant.
        float t1v;
        {
            int c = lane & 7, kk = lane >> 3;   // kk in 0..7, 32-k chunks
            const float* zr = z + (size_t)bi * INF;
            float s = 0.f;
            #pragma unroll
            for (int m = 0; m < 32; m++) s = fmaf(zr[kk * 32 + m], Wt1[(kk * 32 + m) * 8 + c], s);
            s += __shfl_xor(s, 8, 64);
            s += __shfl_xor(s, 16, 64);
            s += __shfl_xor(s, 32, 64);
            int isInt = detect_int(mask);
            t1v = rdbool(mask, bi, isInt) ? s : 0.f;
        }
        // gather packed-We B fragments (cols: We1|We2|We3|0), L1-hot 4KB arrays
        short8 bfrag[4][2];
        {
            #pragma unroll
            for (int t = 0; t < 2; t++) {
                int col = 16 * t + n;
                const float* Wsel = (col < 8) ? We1 : (col < 16 ? We2 : We3);
                int csel = col & 7;
                float mval = (col < 24) ? 1.f : 0.f;
                #pragma unroll
                for (int ks = 0; ks < 4; ks++) {
                    union { short8 s; unsigned short u[8]; } tmp;
                    #pragma unroll
                    for (int jj = 0; jj < 8; jj++) {
                        int k = ks * 32 + q * 8 + jj;
                        tmp.u[jj] = f2bf(Wsel[k * 8 + csel] * mval);
                    }
                    bfrag[ks][t] = tmp.s;
                }
            }
        }
        __builtin_amdgcn_wave_barrier();

        f32x4 ac2[2][2];
        #pragma unroll
        for (int rt = 0; rt < 2; rt++)
            #pragma unroll
            for (int t = 0; t < 2; t++) ac2[rt][t] = 0.f;
        #pragma unroll
        for (int ks = 0; ks < 4; ks++) {
            int k0 = ks * 32 + q * 8;
            short8 a0 = *(const short8*)&Ab[(32 * w + n) * 136 + k0];
            short8 a1 = *(const short8*)&Ab[(32 * w + 16 + n) * 136 + k0];
            #pragma unroll
            for (int t = 0; t < 2; t++) {
                ac2[0][t] = MFMA16(a0, bfrag[ks][t], ac2[0][t]);
                ac2[1][t] = MFMA16(a1, bfrag[ks][t], ac2[1][t]);
            }
        }
        #pragma unroll
        for (int rt = 0; rt < 2; rt++)
            #pragma unroll
            for (int reg = 0; reg < 4; reg++) {
                int row = 32 * w + 16 * rt + 4 * q + reg;
                float v0 = ac2[rt][0][reg];
                if (n < 8) ws[E1T + ((size_t)(b * 128 + row) * 128 + i) * 8 + n] = v0 + t1v;
                else       ws[E2T + ((size_t)(b * 128 + row) * 128 + i) * 8 + (n - 8)] = v0;
                if (n < 8) ws[E3N + ((size_t)bi * 128 + row) * 8 + n] = ac2[rt][1][reg];
            }
        return;
    }
    if (bx < 1024) {
        // ---------- z-row projections (2-way split accumulators for ILP) ----------
        int bn = bx - 512;
        int isInt = detect_int(mask);
        float* zr = (float*)smem;
        zr[tid] = z[(size_t)bn * INF + tid];
        __syncthreads();
        float mk = rdbool(mask, bn, isInt) ? 1.f : 0.f;
        for (int idx = tid; idx < 408; idx += 256) {
            const float* W; int c; size_t dst; int width; bool msk;
            if (idx < 8)        { W = Wt1; c = idx;       dst = TRI1 + (size_t)bn * 8;   width = 8;   msk = true;  }
            else if (idx < 16)  { W = Wt2; c = idx - 8;   dst = TRI2 + (size_t)bn * 8;   width = 8;   msk = true;  }
            else if (idx < 24)  { W = Wt3; c = idx - 16;  dst = TRI3 + (size_t)bn * 8;   width = 8;   msk = true;  }
            else if (idx < 152) { W = Wm1; c = idx - 24;  dst = MSG1 + (size_t)bn * 128; width = 128; msk = true;  }
            else if (idx < 280) { W = Wm2; c = idx - 152; dst = MSG2 + (size_t)bn * 128; width = 128; msk = true;  }
            else                { W = WU1; c = idx - 280; dst = ZWU1 + (size_t)bn * 128; width = 128; msk = false; }
            float a0 = 0.f, a1 = 0.f;
            #pragma unroll 8
            for (int k = 0; k < INF; k += 2) {
                a0 += zr[k] * W[k * width + c];
                a1 += zr[k + 1] * W[(k + 1) * width + c];
            }
            float acc = a0 + a1;
            ws[dst + c] = msk ? acc * mk : acc;
        }
        return;
    }
    if (bx < 1028) {
        // ---------- graph_fts projections ----------
        int b = bx - 1024;
        float* gr = (float*)smem;
        if (tid < 128) gr[tid] = g[b * 128 + tid];
        __syncthreads();
        if (tid < 8) {
            float a = 0.f;
            for (int k = 0; k < 128; k++) a += gr[k] * Wg[k * 8 + tid];
            ws[TRIG + b * 8 + tid] = a;
        } else if (tid >= 128) {
            int c = tid - 128;
            float a = 0.f;
            for (int k = 0; k < 128; k++) a += gr[k] * Wmg[k * 128 + c];
            ws[MSGG + b * 128 + c] = a;
        }
        return;
    }
    // ---------- weight prep (fragment-order), W1/W2/Wme only ----------
    {
        int idx = (bx - 1028) * 256 + tid;   // < 49152
        const float* W = (idx < 16384) ? W1 : (idx < 32768 ? W2 : Wme);
        int local = idx & 16383;
        int f = local >> 3, jj = local & 7;
        int lane = f & 63, fg = f >> 6;
        int t = fg & 7, ks = fg >> 3;
        int n = lane & 15, q = lane >> 4;
        int row = 16 * t + n;
        int k = ks * 32 + q * 8 + jj;
        prep[idx] = f2bf(W[k * 128 + row]);
    }
}

// ============================================================
// K2: bx<256 triplet pooling, bx>=256 pair-MLP (32 rows/wave) with fused
// final LN. grid 768, block 256, LDS 53,248B -> 3 blocks/CU.
//
// r10: Wl split into TWO 8KB slab buffers, software-pipelined: slab s+1's
// global_load_lds is issued into the idle buffer BEFORE slab s's MFMAs,
// so every weight stage hides under MFMA or an epilogue (r8 exposed each
// stage fully between two barriers, 6x per block). Same LDS total, same
// barrier count, same data layout as r8 (the proven structure).
// ============================================================
#define PAIR_GEMM_S(S, WL) do {                                                \
    int kf = (S) * 32 + q * 8;                                                 \
    short8 a0 = *(const short8*)&Ab[(32 * w + n) * 136 + kf];                  \
    short8 a1 = *(const short8*)&Ab[(32 * w + 16 + n) * 136 + kf];             \
    _Pragma("unroll")                                                          \
    for (int t = 0; t < 8; t++) {                                              \
        short8 bt = *(const short8*)&(WL)[(t * 64 + lane) * 8];                \
        acc[0][t] = MFMA16(a0, bt, acc[0][t]);                                 \
        acc[1][t] = MFMA16(a1, bt, acc[1][t]);                                 \
    }                                                                          \
} while (0)

__global__ __launch_bounds__(256, 3) void k_main(
    const float* __restrict__ e, const void* __restrict__ mask, const void* __restrict__ adj,
    const float* __restrict__ ln1s, const float* __restrict__ ln1o,
    const float* __restrict__ ln2s, const float* __restrict__ ln2o,
    const unsigned short* __restrict__ prep, const float* __restrict__ WU3,
    const float* __restrict__ WU2, const float* __restrict__ lnfs, const float* __restrict__ lnfo,
    float* __restrict__ ws, float* __restrict__ out)
{
    int bx = blockIdx.x, tid = threadIdx.x;
    __shared__ __align__(16) unsigned char smem[53248];   // 160KiB/3 exactly
    int lane = tid & 63, w = tid >> 6, q = lane >> 4, n = lane & 15;
    int isInt = detect_int(mask);

    if (bx < 256) {
        // ================= triplet max-plus pooling =================
        int g = bx;
        int j0 = ((g >> 3) & 7) * 16, k0 = (g & 7) * 16, b = g >> 6;
        int wi = w >> 1, wc = w & 1;          // i-half, channel-half
        int tj = lane >> 3, tk = lane & 7;    // 8x8 lanes; outputs (tj,tj+8)x(tk,tk+8)
        int col4 = (tid & 31) * 4, rowgrp = tid >> 5;

        int lenb;
        {
            unsigned long long m0 = __ballot(rdbool(mask, (size_t)b * 128 + lane, isInt));
            unsigned long long m1 = __ballot(rdbool(mask, (size_t)b * 128 + 64 + lane, isInt));
            lenb = __popcll(m0) + __popcll(m1);
        }
        bool needU = (j0 + 15 >= lenb) && (k0 + 15 >= lenb);

        // wave-private staging: P[16][8ii][4c]+pad and Q, stride 36 words
        float* Pb = (float*)smem + w * 1152;
        float* Qb = Pb + 576;

        f32x4 aM[2][2];
        #pragma unroll
        for (int jj = 0; jj < 2; jj++)
            #pragma unroll
            for (int kk = 0; kk < 2; kk++) aM[jj][kk] = NEGF;

        if (!needU) {
            // fast path: every output has mj|mk true -> max over ALL i, one acc set
            for (int ch = 0; ch < 8; ch++) {
                int ibase = wi * 64 + ch * 8;
                #pragma unroll
                for (int r = 0; r < 2; r++) {
                    int f = r * 64 + lane;
                    int jr = f >> 3, ii = f & 7;
                    f32x4 pv = *(const f32x4*)(ws + E1T + (size_t)(b * 128 + j0 + jr) * 1024 + (ibase + ii) * 8 + wc * 4);
                    f32x4 qv = *(const f32x4*)(ws + E2T + (size_t)(b * 128 + k0 + jr) * 1024 + (ibase + ii) * 8 + wc * 4);
                    *(f32x4*)(Pb + jr * 36 + ii * 4) = pv;
                    *(f32x4*)(Qb + jr * 36 + ii * 4) = qv;
                }
                __builtin_amdgcn_wave_barrier();
                #pragma unroll
                for (int ii = 0; ii < 8; ii++) {
                    f32x4 p0 = *(const f32x4*)(Pb + tj * 36 + ii * 4);
                    f32x4 p1 = *(const f32x4*)(Pb + (tj + 8) * 36 + ii * 4);
                    f32x4 q0 = *(const f32x4*)(Qb + tk * 36 + ii * 4);
                    f32x4 q1 = *(const f32x4*)(Qb + (tk + 8) * 36 + ii * 4);
                    aM[0][0] = __builtin_elementwise_max(aM[0][0], p0 + q0);
                    aM[0][1] = __builtin_elementwise_max(aM[0][1], p0 + q1);
                    aM[1][0] = __builtin_elementwise_max(aM[1][0], p1 + q0);
                    aM[1][1] = __builtin_elementwise_max(aM[1][1], p1 + q1);
                }
            }
        } else {
            f32x4 aU[2][2];
            #pragma unroll
            for (int jj = 0; jj < 2; jj++)
                #pragma unroll
                for (int kk = 0; kk < 2; kk++) aU[jj][kk] = NEGF;
            unsigned long long mball = __ballot(rdbool(mask, (size_t)b * 128 + wi * 64 + lane, isInt));
            for (int ch = 0; ch < 8; ch++) {
                int ibase = wi * 64 + ch * 8;
                #pragma unroll
                for (int r = 0; r < 2; r++) {
                    int f = r * 64 + lane;
                    int jr = f >> 3, ii = f & 7;
                    f32x4 pv = *(const f32x4*)(ws + E1T + (size_t)(b * 128 + j0 + jr) * 1024 + (ibase + ii) * 8 + wc * 4);
                    f32x4 qv = *(const f32x4*)(ws + E2T + (size_t)(b * 128 + k0 + jr) * 1024 + (ibase + ii) * 8 + wc * 4);
                    *(f32x4*)(Pb + jr * 36 + ii * 4) = pv;
                    *(f32x4*)(Qb + jr * 36 + ii * 4) = qv;
                }
                __builtin_amdgcn_wave_barrier();
                #pragma unroll
                for (int ii = 0; ii < 8; ii++) {
                    f32x4 p0 = *(const f32x4*)(Pb + tj * 36 + ii * 4);
                    f32x4 p1 = *(const f32x4*)(Pb + (tj + 8) * 36 + ii * 4);
                    f32x4 q0 = *(const f32x4*)(Qb + tk * 36 + ii * 4);
                    f32x4 q1 = *(const f32x4*)(Qb + (tk + 8) * 36 + ii * 4);
                    f32x4 v00 = p0 + q0, v01 = p0 + q1, v10 = p1 + q0, v11 = p1 + q1;
                    if ((mball >> (ch * 8 + ii)) & 1) {
                        aM[0][0] = __builtin_elementwise_max(aM[0][0], v00);
                        aM[0][1] = __builtin_elementwise_max(aM[0][1], v01);
                        aM[1][0] = __builtin_elementwise_max(aM[1][0], v10);
                        aM[1][1] = __builtin_elementwise_max(aM[1][1], v11);
                    } else {
                        aU[0][0] = __builtin_elementwise_max(aU[0][0], v00);
                        aU[0][1] = __builtin_elementwise_max(aU[0][1], v01);
                        aU[1][0] = __builtin_elementwise_max(aU[1][0], v10);
                        aU[1][1] = __builtin_elementwise_max(aU[1][1], v11);
                    }
                }
            }
            // outputs with mj|mk include unmasked-i contributions too
            bool mj[2], mk2[2];
            mj[0]  = (j0 + tj)     < lenb;
            mj[1]  = (j0 + tj + 8) < lenb;
            mk2[0] = (k0 + tk)     < lenb;
            mk2[1] = (k0 + tk + 8) < lenb;
            #pragma unroll
            for (int jj = 0; jj < 2; jj++)
                #pragma unroll
                for (int kk = 0; kk < 2; kk++)
                    if (mj[jj] | mk2[kk])
                        aM[jj][kk] = __builtin_elementwise_max(aM[jj][kk], aU[jj][kk]);
        }
        __syncthreads();   // all staging reads done; alias staging region as 'pooled'
        float* pooled = (float*)smem;   // [8][260] c-major
        float4 wvr[8];
        #pragma unroll
        for (int c = 0; c < 8; c++) wvr[c] = *(const float4*)(WU3 + c * 128 + col4);

        if (wi == 0) {
            #pragma unroll
            for (int jj = 0; jj < 2; jj++)
                #pragma unroll
                for (int kk = 0; kk < 2; kk++) {
                    int p = (tj + 8 * jj) * 16 + (tk + 8 * kk);
                    #pragma unroll
                    for (int cc = 0; cc < 4; cc++)
                        pooled[(wc * 4 + cc) * 260 + p] = aM[jj][kk][cc];
                }
        }
        __syncthreads();
        if (wi == 1) {
            const float* tg = ws + TRIG + (size_t)b * 8 + wc * 4;
            #pragma unroll
            for (int jj = 0; jj < 2; jj++)
                #pragma unroll
                for (int kk = 0; kk < 2; kk++) {
                    int jv = j0 + tj + 8 * jj, kv = k0 + tk + 8 * kk;
                    const float* t2 = ws + TRI2 + (size_t)(b * 128 + jv) * 8 + wc * 4;
                    const float* t3 = ws + TRI3 + (size_t)(b * 128 + kv) * 8 + wc * 4;
                    const float* e3 = ws + E3N + ((size_t)(b * 128 + jv) * 128 + kv) * 8 + wc * 4;
                    int p = (tj + 8 * jj) * 16 + (tk + 8 * kk);
                    #pragma unroll
                    for (int cc = 0; cc < 4; cc++) {
                        int idx = (wc * 4 + cc) * 260 + p;
                        pooled[idx] = fmaxf(pooled[idx], aM[jj][kk][cc]) + t2[cc] + t3[cc] + e3[cc] + tg[cc];
                    }
                }
        }
        __syncthreads();
        // epilogue: relu(pooled @ WU3); pooled reads broadcast, no LDS weights
        #pragma unroll
        for (int pass = 0; pass < 32; pass++) {
            int p = pass * 8 + rowgrp;
            float4 s = { 0.f, 0.f, 0.f, 0.f };
            #pragma unroll
            for (int c = 0; c < 8; c++) {
                float pv = pooled[c * 260 + p];
                s.x += pv * wvr[c].x; s.y += pv * wvr[c].y;
                s.z += pv * wvr[c].z; s.w += pv * wvr[c].w;
            }
            s.x = fmaxf(s.x, 0.f); s.y = fmaxf(s.y, 0.f);
            s.z = fmaxf(s.z, 0.f); s.w = fmaxf(s.w, 0.f);
            int pj = p >> 4, pk = p & 15;
            *(float4*)(out + O_TRI + ((size_t)(b * 128 + j0 + pj) * 128 + (k0 + pk)) * 128 + col4) = s;
        }
        return;
    }

    // ================= pair MLP: block = one (b,j), 32 rows/wave =================
    unsigned short* Ab = (unsigned short*)smem;                       // [128][136] 34816B
    float* pw = (float*)(smem + 34816);                               // [4][128]   2048B
    unsigned short* Wl0 = (unsigned short*)(smem + 36864);            // 8192B slab buf 0
    unsigned short* Wl1 = (unsigned short*)(smem + 45056);            // 8192B slab buf 1
    // fused final-LN scratch aliases Wl0 (written only after the barrier
    // that retires the last Wl0 reads; dead blocks never stage Wl)
    float* mrowL = (float*)(smem + 36864);    // [128]
    float* partL = mrowL + 128;               // [256]
    float* redL  = partL + 256;               // [4]
    int bj = bx - 256;
    int b = bj >> 7, j = bj & 127;

    int lenb;
    {
        unsigned long long m0 = __ballot(rdbool(mask, (size_t)b * 128 + lane, isInt));
        unsigned long long m1 = __ballot(rdbool(mask, (size_t)b * 128 + 64 + lane, isInt));
        lenb = __popcll(m0) + __popcll(m1);
    }
    bool live = (j < lenb);   // block-uniform

    if (live) {
        bool waveActive = (32 * w) < lenb;

        stage_q(prep, WMET_OFF, Wl0, w, lane);      // Wme.s0 in flight during e-stage
        if (waveActive) {
            int half = lane >> 5, c4 = (lane & 31) * 4;
            #pragma unroll
            for (int it = 0; it < 16; it++) {
                int row = 32 * w + 2 * it + half;
                float4 v = *(const float4*)(e + (((size_t)b * 128 + row) * 128 + j) * 128 + c4);
                unsigned* dst = (unsigned*)&Ab[row * 136 + c4];
                dst[0] = pack2(v.x, v.y);
                dst[1] = pack2(v.z, v.w);
            }
        }
        __syncthreads();                            // Wme.s0 + Ab ready

        float colmax[8];
        #pragma unroll
        for (int t = 0; t < 8; t++) colmax[t] = NEGF;
        float adjm[2][4];
        f32x4 acc[2][8];

        // ---- GEMM1: X @ Wme (slab-pipelined) ----
        #pragma unroll
        for (int rt = 0; rt < 2; rt++)
            #pragma unroll
            for (int t = 0; t < 8; t++) acc[rt][t] = 0.f;
        stage_q(prep, WMET_OFF + 4096, Wl1, w, lane);   // s1 hides under s0 MFMAs
        if (waveActive) PAIR_GEMM_S(0, Wl0);
        __syncthreads();                                // s1 ready; Wl0 reads retired
        stage_q(prep, WMET_OFF + 8192, Wl0, w, lane);
        if (waveActive) PAIR_GEMM_S(1, Wl1);
        __syncthreads();
        stage_q(prep, WMET_OFF + 12288, Wl1, w, lane);
        if (waveActive) PAIR_GEMM_S(2, Wl0);
        __syncthreads();
        stage_q(prep, W1T_OFF, Wl0, w, lane);           // W1.s0 hides under s3 + epilogue1
        if (waveActive) PAIR_GEMM_S(3, Wl1);

        if (waveActive) {
            float msum[8];
            #pragma unroll
            for (int t = 0; t < 8; t++)
                msum[t] = ws[MSG1 + (size_t)bj * 128 + 16 * t + n] + ws[MSGG + (size_t)b * 128 + 16 * t + n];
            float rs[2][4], rss[2][4];
            #pragma unroll
            for (int rt = 0; rt < 2; rt++)
                #pragma unroll
                for (int reg = 0; reg < 4; reg++) {
                    int row = 32 * w + 16 * rt + 4 * q + reg;
                    bool av = rdbool(adj, ((size_t)b * 128 + row) * 128 + j, isInt);
                    adjm[rt][reg] = av ? 1.f : 0.f;
                    float s = 0.f, ssq = 0.f;
                    #pragma unroll
                    for (int t = 0; t < 8; t++) {
                        float v = acc[rt][t][reg] * adjm[rt][reg]
                                + ws[MSG2 + ((size_t)b * 128 + row) * 128 + 16 * t + n] + msum[t];
                        acc[rt][t][reg] = v;
                        s += v; ssq += v * v;
                    }
                    rs[rt][reg] = s; rss[rt][reg] = ssq;
                }
            #pragma unroll
            for (int d = 1; d < 16; d <<= 1) {
                #pragma unroll
                for (int rt = 0; rt < 2; rt++)
                    #pragma unroll
                    for (int reg = 0; reg < 4; reg++) {
                        rs[rt][reg]  += __shfl_xor(rs[rt][reg], d, 64);
                        rss[rt][reg] += __shfl_xor(rss[rt][reg], d, 64);
                    }
            }
            float s1v[8], o1v[8];
            #pragma unroll
            for (int t = 0; t < 8; t++) { s1v[t] = ln1s[16 * t + n]; o1v[t] = ln1o[16 * t + n]; }
            #pragma unroll
            for (int rt = 0; rt < 2; rt++)
                #pragma unroll
                for (int reg = 0; reg < 4; reg++) {
                    float mu = rs[rt][reg] * (1.f / 128);
                    float inv = rsqrtf(rss[rt][reg] * (1.f / 128) - mu * mu + EPSF);
                    int row = 32 * w + 16 * rt + 4 * q + reg;
                    #pragma unroll
                    for (int t = 0; t < 8; t++) {
                        float v = fmaxf(s1v[t] * inv * (acc[rt][t][reg] - mu) + o1v[t], 0.f);
                        Ab[row * 136 + 16 * t + n] = f2bf(v);
                    }
                }
        }
        __syncthreads();                            // W1.s0 ready; epilogue1 done

        // ---- GEMM2: relu(LN1) @ W1 (slab-pipelined) ----
        #pragma unroll
        for (int rt = 0; rt < 2; rt++)
            #pragma unroll
            for (int t = 0; t < 8; t++) acc[rt][t] = 0.f;
        stage_q(prep, W1T_OFF + 4096, Wl1, w, lane);
        if (waveActive) PAIR_GEMM_S(0, Wl0);
        __syncthreads();
        stage_q(prep, W1T_OFF + 8192, Wl0, w, lane);
        if (waveActive) PAIR_GEMM_S(1, Wl1);
        __syncthreads();
        stage_q(prep, W1T_OFF + 12288, Wl1, w, lane);
        if (waveActive) PAIR_GEMM_S(2, Wl0);
        __syncthreads();
        stage_q(prep, W2T_OFF, Wl0, w, lane);           // W2.s0 hides under s3 + epilogue2
        if (waveActive) PAIR_GEMM_S(3, Wl1);

        if (waveActive) {
            float rs[2][4], rss[2][4];
            #pragma unroll
            for (int rt = 0; rt < 2; rt++)
                #pragma unroll
                for (int reg = 0; reg < 4; reg++) {
                    float s = 0.f, ssq = 0.f;
                    #pragma unroll
                    for (int t = 0; t < 8; t++) { float v = acc[rt][t][reg]; s += v; ssq += v * v; }
                    rs[rt][reg] = s; rss[rt][reg] = ssq;
                }
            #pragma unroll
            for (int d = 1; d < 16; d <<= 1) {
                #pragma unroll
                for (int rt = 0; rt < 2; rt++)
                    #pragma unroll
                    for (int reg = 0; reg < 4; reg++) {
                        rs[rt][reg]  += __shfl_xor(rs[rt][reg], d, 64);
                        rss[rt][reg] += __shfl_xor(rss[rt][reg], d, 64);
                    }
            }
            float s2v[8], o2v[8];
            #pragma unroll
            for (int t = 0; t < 8; t++) { s2v[t] = ln2s[16 * t + n]; o2v[t] = ln2o[16 * t + n]; }
            #pragma unroll
            for (int rt = 0; rt < 2; rt++)
                #pragma unroll
                for (int reg = 0; reg < 4; reg++) {
                    float mu = rs[rt][reg] * (1.f / 128);
                    float inv = rsqrtf(rss[rt][reg] * (1.f / 128) - mu * mu + EPSF);
                    int row = 32 * w + 16 * rt + 4 * q + reg;
                    #pragma unroll
                    for (int t = 0; t < 8; t++) {
                        float v = fmaxf(s2v[t] * inv * (acc[rt][t][reg] - mu) + o2v[t], 0.f);
                        Ab[row * 136 + 16 * t + n] = f2bf(v);
                    }
                }
        }
        __syncthreads();                            // W2.s0 ready; epilogue2 done

        // ---- GEMM3: relu(LN2) @ W2 (slab-pipelined) ----
        #pragma unroll
        for (int rt = 0; rt < 2; rt++)
            #pragma unroll
            for (int t = 0; t < 8; t++) acc[rt][t] = 0.f;
        stage_q(prep, W2T_OFF + 4096, Wl1, w, lane);
        if (waveActive) PAIR_GEMM_S(0, Wl0);
        __syncthreads();
        stage_q(prep, W2T_OFF + 8192, Wl0, w, lane);
        if (waveActive) PAIR_GEMM_S(1, Wl1);
        __syncthreads();
        stage_q(prep, W2T_OFF + 12288, Wl1, w, lane);
        if (waveActive) PAIR_GEMM_S(2, Wl0);
        __syncthreads();
        if (waveActive) {
            PAIR_GEMM_S(3, Wl1);
            #pragma unroll
            for (int rt = 0; rt < 2; rt++)
                #pragma unroll
                for (int reg = 0; reg < 4; reg++) {
                    if (adjm[rt][reg] > 0.f) {
                        #pragma unroll
                        for (int t = 0; t < 8; t++) colmax[t] = fmaxf(colmax[t], acc[rt][t][reg]);
                    }
                }
        }
        #pragma unroll
        for (int t = 0; t < 8; t++) {
            colmax[t] = fmaxf(colmax[t], __shfl_xor(colmax[t], 16, 64));
            colmax[t] = fmaxf(colmax[t], __shfl_xor(colmax[t], 32, 64));
        }
        if (lane < 16) {
            #pragma unroll
            for (int t = 0; t < 8; t++) pw[w * 128 + 16 * t + lane] = colmax[t];
        }
        __syncthreads();                            // last Wl0 reads long retired; mrowL may alias
        if (tid < 128) {
            float mx = fmaxf(fmaxf(pw[tid], pw[128 + tid]), fmaxf(pw[256 + tid], pw[384 + tid]));
            mrowL[tid] = mx;
            out[O_MSG + (size_t)bj * 128 + tid] = mx;
        }
    } else {
        // dead column: msgs row = NEGF exactly as the all-false colmax path
        if (tid < 128) {
            mrowL[tid] = NEGF;
            out[O_MSG + (size_t)bj * 128 + tid] = NEGF;
        }
    }
    __syncthreads();

    // ---- fused final LN: ret = LN(z@WU1 + msgs@WU2) ----
    {
        int c = tid & 127, hf = tid >> 7;
        int kb = hf * 64;
        float a0 = 0.f, a1 = 0.f;
        #pragma unroll 8
        for (int k = 0; k < 64; k += 2) {
            a0 = fmaf(mrowL[kb + k],     WU2[(size_t)(kb + k) * 128 + c],     a0);
            a1 = fmaf(mrowL[kb + k + 1], WU2[(size_t)(kb + k + 1) * 128 + c], a1);
        }
        partL[hf * 128 + c] = a0 + a1;
        __syncthreads();
        float y = ws[ZWU1 + (size_t)bj * 128 + c] + partL[c] + partL[128 + c];
        float s = y, ss = y * y;
        #pragma unroll
        for (int d = 1; d < 64; d <<= 1) { s += __shfl_xor(s, d, 64); ss += __shfl_xor(ss, d, 64); }
        if (tid == 0 || tid == 64) { redL[(tid >> 6) * 2] = s; redL[(tid >> 6) * 2 + 1] = ss; }
        __syncthreads();
        float S = redL[0] + redL[2], SS = redL[1] + redL[3];
        float m_ = S * (1.f / 128), v_ = SS * (1.f / 128) - m_ * m_;
        float r = rsqrtf(v_ + EPSF);
        if (tid < 128) out[O_RET + (size_t)bj * 128 + c] = lnfs[c] * r * (y - m_) + lnfo[c];
    }
}

// ============================================================
extern "C" void kernel_launch(void* const* d_in, const int* in_sizes, int n_in,
                              void* d_out, int out_size, void* d_ws, size_t ws_size,
                              hipStream_t stream)
{
    const float* z    = (const float*)d_in[0];
    const float* e    = (const float*)d_in[1];
    const float* gf   = (const float*)d_in[2];
    const void*  mask = d_in[3];
    const void*  adj  = d_in[4];
    const float* Wt1 = (const float*)d_in[5];
    const float* Wt2 = (const float*)d_in[6];
    const float* Wt3 = (const float*)d_in[7];
    const float* We1 = (const float*)d_in[8];
    const float* We2 = (const float*)d_in[9];
    const float* We3 = (const float*)d_in[10];
    const float* Wg  = (const float*)d_in[11];
    const float* Wm1 = (const float*)d_in[12];
    const float* Wm2 = (const float*)d_in[13];
    const float* Wme = (const float*)d_in[14];
    const float* Wmg = (const float*)d_in[15];
    const float* ln1s = (const float*)d_in[16];
    const float* ln1o = (const float*)d_in[17];
    const float* W1   = (const float*)d_in[18];
    const float* ln2s = (const float*)d_in[19];
    const float* ln2o = (const float*)d_in[20];
    const float* W2   = (const float*)d_in[21];
    const float* WU1  = (const float*)d_in[22];
    const float* WU2  = (const float*)d_in[23];
    const float* WU3  = (const float*)d_in[24];
    const float* lnfs = (const float*)d_in[25];
    const float* lnfo = (const float*)d_in[26];
    float* out = (float*)d_out;
    float* ws  = (float*)d_ws;
    unsigned short* prep = (unsigned short*)(ws + PREPF);

    hipLaunchKernelGGL(k_pre, dim3(1220), dim3(256), 0, stream,
                       z, e, mask, Wt1, Wt2, Wt3, Wm1, Wm2, WU1, gf, Wg, Wmg,
                       W1, W2, Wme, We1, We2, We3, ws, prep);
    hipLaunchKernelGGL(k_main, dim3(768), dim3(256), 0, stream,
                       e, mask, adj, ln1s, ln1o, ln2s, ln2o, prep, WU3,
                       WU2, lnfs, lnfo, ws, out);
}

// Round 11
// 176.205 us; speedup vs baseline: 1.0407x; 1.0312x over previous
//
#include <hip/hip_runtime.h>

// Problem constants
#define BN   4
#define NN   128
#define INF  256
#define EF   128
#define OUTF 128
#define EPSF 1e-5f
#define NEGF -998244352.0f   // bf16(1e9); matches the bf16-rounded np reference

typedef __attribute__((ext_vector_type(8))) short short8;
typedef __attribute__((ext_vector_type(4))) float f32x4;

#define MFMA16(a, b, c) __builtin_amdgcn_mfma_f32_16x16x32_bf16(a, b, c, 0, 0, 0)

__device__ __forceinline__ unsigned short f2bf(float f) {
    unsigned u = __float_as_uint(f);
    u += 0x7fffu + ((u >> 16) & 1u);
    return (unsigned short)(u >> 16);
}
__device__ __forceinline__ unsigned pack2(float a, float b) {
    return (unsigned)f2bf(a) | ((unsigned)f2bf(b) << 16);
}

// ---- workspace layout (float offsets) ----
constexpr size_t TRI1 = 0;            // B*N*8   tri_1 (masked)  [folded into E1T; kept]
constexpr size_t TRI2 = 4096;
constexpr size_t TRI3 = 8192;
constexpr size_t MSG1 = 12288;        // B*N*128 msg_1 (masked)
constexpr size_t MSG2 = 77824;
constexpr size_t ZWU1 = 143360;
constexpr size_t TRIG = 208896;       // B*8
constexpr size_t MSGG = 209920;       // B*128
constexpr size_t E1T  = 210944;       // B*N*N*8  fp32 [b][j][i][c]  (tri_e1 + tri_1 folded)
constexpr size_t E2T  = 735232;       // B*N*N*8  fp32 [b][k][i][c]
constexpr size_t E3N  = 1259520;      // B*N*N*8  fp32 [b][j][k][c]
constexpr size_t PREPF = 1914880;     // bf16 prepped weights (ushort region)

// prep (ushort units), MFMA-fragment order:
// ((ks*8 + t)*64 + lane)*8 + jj == W^T[16t + (lane&15)][ks*32 + (lane>>4)*8 + jj]
// Each ks-slab is 4096 ushorts (8KB); a half-set (2 ks) is 8192 ushorts (16KB).
constexpr int W1T_OFF  = 0;
constexpr int W2T_OFF  = 16384;
constexpr int WMET_OFF = 32768;

// ---- output layout (float offsets): ret, msgs, tri_msgs ----
constexpr size_t O_RET = 0;
constexpr size_t O_MSG = 65536;
constexpr size_t O_TRI = 131072;

__device__ __forceinline__ int detect_int(const void* mask) {
    const unsigned char* m = (const unsigned char*)mask;
    return (m[1] | m[2] | m[3]) == 0 ? 1 : 0;
}
__device__ __forceinline__ bool rdbool(const void* p, size_t idx, int isInt) {
    if (isInt) return ((const int*)p)[idx] != 0;
    return ((const unsigned char*)p)[idx] != 0;
}

// direct global->LDS copy of one 16KB weight HALF-set (r6: no VGPR round
// trip, no spill). Each wave copies 4KB: wave-uniform LDS base + lane*16.
__device__ __forceinline__ void stage_h(const unsigned short* __restrict__ prep, int offU,
                                        unsigned short* Wl, int w, int lane)
{
    const char* g = (const char*)(prep + offU) + w * 4096 + lane * 16;
    char* l = (char*)Wl + w * 4096;   // wave-uniform
    #pragma unroll
    for (int r = 0; r < 4; r++) {
        __builtin_amdgcn_global_load_lds(
            (const __attribute__((address_space(1))) void*)(g + r * 1024),
            (__attribute__((address_space(3))) void*)(l + r * 1024),
            16, 0, 0);
    }
}

// ============================================================
// K1: tri-e projection (0..511) + z proj (512..1023) + graph (1024..1027)
//     + weight prep (1028..1219).  256 thr.
// ============================================================
__global__ __launch_bounds__(256, 4) void k_pre(
    const float* __restrict__ z, const float* __restrict__ e, const void* __restrict__ mask,
    const float* __restrict__ Wt1, const float* __restrict__ Wt2, const float* __restrict__ Wt3,
    const float* __restrict__ Wm1, const float* __restrict__ Wm2, const float* __restrict__ WU1,
    const float* __restrict__ g, const float* __restrict__ Wg, const float* __restrict__ Wmg,
    const float* __restrict__ W1, const float* __restrict__ W2, const float* __restrict__ Wme,
    const float* __restrict__ We1, const float* __restrict__ We2, const float* __restrict__ We3,
    float* __restrict__ ws, unsigned short* __restrict__ prep)
{
    int bx = blockIdx.x, tid = threadIdx.x;
    __shared__ __align__(16) unsigned char smem[128 * 136 * 2];

    if (bx < 512) {
        // ---------- tri-e projection: block = one (b,i) ----------
        unsigned short* Ab = (unsigned short*)smem;
        int bi = bx;
        int b = bi >> 7, i = bi & 127;
        int lane = tid & 63, w = tid >> 6, q = lane >> 4, n = lane & 15;
        {
            int half = lane >> 5, c4 = (lane & 31) * 4;
            #pragma unroll
            for (int it = 0; it < 16; it++) {
                int row = 32 * w + 2 * it + half;
                float4 v = *(const float4*)(e + (size_t)bi * 16384 + (size_t)row * 128 + c4);
                unsigned* dst = (unsigned*)&Ab[row * 136 + c4];
                dst[0] = pack2(v.x, v.y);
                dst[1] = pack2(v.z, v.w);
            }
        }
        // t1 row for node i: masked z[b,i,:]@Wt1, per-wave redundant.
        float t1v;
        {
            int c = lane & 7, kk = lane >> 3;   // kk in 0..7, 32-k chunks
            const float* zr = z + (size_t)bi * INF;
            float s = 0.f;
            #pragma unroll
            for (int m = 0; m < 32; m++) s = fmaf(zr[kk * 32 + m], Wt1[(kk * 32 + m) * 8 + c], s);
            s += __shfl_xor(s, 8, 64);
            s += __shfl_xor(s, 16, 64);
            s += __shfl_xor(s, 32, 64);
            int isInt = detect_int(mask);
            t1v = rdbool(mask, bi, isInt) ? s : 0.f;
        }
        // gather packed-We B fragments (cols: We1|We2|We3|0), L1-hot 4KB arrays
        short8 bfrag[4][2];
        {
            #pragma unroll
            for (int t = 0; t < 2; t++) {
                int col = 16 * t + n;
                const float* Wsel = (col < 8) ? We1 : (col < 16 ? We2 : We3);
                int csel = col & 7;
                float mval = (col < 24) ? 1.f : 0.f;
                #pragma unroll
                for (int ks = 0; ks < 4; ks++) {
                    union { short8 s; unsigned short u[8]; } tmp;
                    #pragma unroll
                    for (int jj = 0; jj < 8; jj++) {
                        int k = ks * 32 + q * 8 + jj;
                        tmp.u[jj] = f2bf(Wsel[k * 8 + csel] * mval);
                    }
                    bfrag[ks][t] = tmp.s;
                }
            }
        }
        __builtin_amdgcn_wave_barrier();

        f32x4 ac2[2][2];
        #pragma unroll
        for (int rt = 0; rt < 2; rt++)
            #pragma unroll
            for (int t = 0; t < 2; t++) ac2[rt][t] = 0.f;
        #pragma unroll
        for (int ks = 0; ks < 4; ks++) {
            int k0 = ks * 32 + q * 8;
            short8 a0 = *(const short8*)&Ab[(32 * w + n) * 136 + k0];
            short8 a1 = *(const short8*)&Ab[(32 * w + 16 + n) * 136 + k0];
            #pragma unroll
            for (int t = 0; t < 2; t++) {
                ac2[0][t] = MFMA16(a0, bfrag[ks][t], ac2[0][t]);
                ac2[1][t] = MFMA16(a1, bfrag[ks][t], ac2[1][t]);
            }
        }
        #pragma unroll
        for (int rt = 0; rt < 2; rt++)
            #pragma unroll
            for (int reg = 0; reg < 4; reg++) {
                int row = 32 * w + 16 * rt + 4 * q + reg;
                float v0 = ac2[rt][0][reg];
                if (n < 8) ws[E1T + ((size_t)(b * 128 + row) * 128 + i) * 8 + n] = v0 + t1v;
                else       ws[E2T + ((size_t)(b * 128 + row) * 128 + i) * 8 + (n - 8)] = v0;
                if (n < 8) ws[E3N + ((size_t)bi * 128 + row) * 8 + n] = ac2[rt][1][reg];
            }
        return;
    }
    if (bx < 1024) {
        // ---------- z-row projections (2-way split accumulators for ILP) ----------
        int bn = bx - 512;
        int isInt = detect_int(mask);
        float* zr = (float*)smem;
        zr[tid] = z[(size_t)bn * INF + tid];
        __syncthreads();
        float mk = rdbool(mask, bn, isInt) ? 1.f : 0.f;
        for (int idx = tid; idx < 408; idx += 256) {
            const float* W; int c; size_t dst; int width; bool msk;
            if (idx < 8)        { W = Wt1; c = idx;       dst = TRI1 + (size_t)bn * 8;   width = 8;   msk = true;  }
            else if (idx < 16)  { W = Wt2; c = idx - 8;   dst = TRI2 + (size_t)bn * 8;   width = 8;   msk = true;  }
            else if (idx < 24)  { W = Wt3; c = idx - 16;  dst = TRI3 + (size_t)bn * 8;   width = 8;   msk = true;  }
            else if (idx < 152) { W = Wm1; c = idx - 24;  dst = MSG1 + (size_t)bn * 128; width = 128; msk = true;  }
            else if (idx < 280) { W = Wm2; c = idx - 152; dst = MSG2 + (size_t)bn * 128; width = 128; msk = true;  }
            else                { W = WU1; c = idx - 280; dst = ZWU1 + (size_t)bn * 128; width = 128; msk = false; }
            float a0 = 0.f, a1 = 0.f;
            #pragma unroll 8
            for (int k = 0; k < INF; k += 2) {
                a0 += zr[k] * W[k * width + c];
                a1 += zr[k + 1] * W[(k + 1) * width + c];
            }
            float acc = a0 + a1;
            ws[dst + c] = msk ? acc * mk : acc;
        }
        return;
    }
    if (bx < 1028) {
        // ---------- graph_fts projections ----------
        int b = bx - 1024;
        float* gr = (float*)smem;
        if (tid < 128) gr[tid] = g[b * 128 + tid];
        __syncthreads();
        if (tid < 8) {
            float a = 0.f;
            for (int k = 0; k < 128; k++) a += gr[k] * Wg[k * 8 + tid];
            ws[TRIG + b * 8 + tid] = a;
        } else if (tid >= 128) {
            int c = tid - 128;
            float a = 0.f;
            for (int k = 0; k < 128; k++) a += gr[k] * Wmg[k * 128 + c];
            ws[MSGG + b * 128 + c] = a;
        }
        return;
    }
    // ---------- weight prep (fragment-order), W1/W2/Wme only ----------
    {
        int idx = (bx - 1028) * 256 + tid;   // < 49152
        const float* W = (idx < 16384) ? W1 : (idx < 32768 ? W2 : Wme);
        int local = idx & 16383;
        int f = local >> 3, jj = local & 7;
        int lane = f & 63, fg = f >> 6;
        int t = fg & 7, ks = fg >> 3;
        int n = lane & 15, q = lane >> 4;
        int row = 16 * t + n;
        int k = ks * 32 + q * 8 + jj;
        prep[idx] = f2bf(W[k * 128 + row]);
    }
}

// ============================================================
// K2: bx<256 triplet pooling, bx>=256 pair-MLP (32 rows/wave) WITH the
// final LN fused into the pair tail: ret row bn depends only on pair
// block bn's msgs row + ZWU1 + L2-hot WU2 -> no kernel boundary needed.
// 'live' (j<lenb) is block-uniform so barriers stay uniform; dead blocks
// take the NEGF path and join at the fused-LN barrier.
// grid 768, block 256, LDS 53,248B -> 3 blocks/CU, one scheduling round.
// ============================================================
#define PAIR_GEMM_H(HS) do {                                                   \
    _Pragma("unroll")                                                          \
    for (int ls = 0; ls < 2; ls++) {                                           \
        int kf = (2 * (HS) + ls) * 32 + q * 8;                                 \
        short8 a0 = *(const short8*)&Ab[(32 * w + n) * 136 + kf];              \
        short8 a1 = *(const short8*)&Ab[(32 * w + 16 + n) * 136 + kf];         \
        _Pragma("unroll")                                                      \
        for (int t = 0; t < 8; t++) {                                          \
            short8 bt = *(const short8*)&Wl[((ls * 8 + t) * 64 + lane) * 8];   \
            acc[0][t] = MFMA16(a0, bt, acc[0][t]);                             \
            acc[1][t] = MFMA16(a1, bt, acc[1][t]);                             \
        }                                                                      \
    }                                                                          \
} while (0)

__global__ __launch_bounds__(256, 3) void k_main(
    const float* __restrict__ e, const void* __restrict__ mask, const void* __restrict__ adj,
    const float* __restrict__ ln1s, const float* __restrict__ ln1o,
    const float* __restrict__ ln2s, const float* __restrict__ ln2o,
    const unsigned short* __restrict__ prep, const float* __restrict__ WU3,
    const float* __restrict__ WU2, const float* __restrict__ lnfs, const float* __restrict__ lnfo,
    float* __restrict__ ws, float* __restrict__ out)
{
    int bx = blockIdx.x, tid = threadIdx.x;
    __shared__ __align__(16) unsigned char smem[53248];   // 160KiB/3 exactly
    int lane = tid & 63, w = tid >> 6, q = lane >> 4, n = lane & 15;
    int isInt = detect_int(mask);

    if (bx < 256) {
        // ================= triplet max-plus pooling =================
        int g = bx;
        int j0 = ((g >> 3) & 7) * 16, k0 = (g & 7) * 16, b = g >> 6;
        int wi = w >> 1, wc = w & 1;          // i-half, channel-half
        int tj = lane >> 3, tk = lane & 7;    // 8x8 lanes; outputs (tj,tj+8)x(tk,tk+8)
        int col4 = (tid & 31) * 4, rowgrp = tid >> 5;

        int lenb;
        {
            unsigned long long m0 = __ballot(rdbool(mask, (size_t)b * 128 + lane, isInt));
            unsigned long long m1 = __ballot(rdbool(mask, (size_t)b * 128 + 64 + lane, isInt));
            lenb = __popcll(m0) + __popcll(m1);
        }
        bool needU = (j0 + 15 >= lenb) && (k0 + 15 >= lenb);

        // wave-private staging: P[16][8ii][4c]+pad and Q, stride 36 words
        float* Pb = (float*)smem + w * 1152;
        float* Qb = Pb + 576;

        f32x4 aM[2][2];
        #pragma unroll
        for (int jj = 0; jj < 2; jj++)
            #pragma unroll
            for (int kk = 0; kk < 2; kk++) aM[jj][kk] = NEGF;

        if (!needU) {
            // fast path: every output has mj|mk true -> max over ALL i, one acc set
            for (int ch = 0; ch < 8; ch++) {
                int ibase = wi * 64 + ch * 8;
                #pragma unroll
                for (int r = 0; r < 2; r++) {
                    int f = r * 64 + lane;
                    int jr = f >> 3, ii = f & 7;
                    f32x4 pv = *(const f32x4*)(ws + E1T + (size_t)(b * 128 + j0 + jr) * 1024 + (ibase + ii) * 8 + wc * 4);
                    f32x4 qv = *(const f32x4*)(ws + E2T + (size_t)(b * 128 + k0 + jr) * 1024 + (ibase + ii) * 8 + wc * 4);
                    *(f32x4*)(Pb + jr * 36 + ii * 4) = pv;
                    *(f32x4*)(Qb + jr * 36 + ii * 4) = qv;
                }
                __builtin_amdgcn_wave_barrier();
                #pragma unroll
                for (int ii = 0; ii < 8; ii++) {
                    f32x4 p0 = *(const f32x4*)(Pb + tj * 36 + ii * 4);
                    f32x4 p1 = *(const f32x4*)(Pb + (tj + 8) * 36 + ii * 4);
                    f32x4 q0 = *(const f32x4*)(Qb + tk * 36 + ii * 4);
                    f32x4 q1 = *(const f32x4*)(Qb + (tk + 8) * 36 + ii * 4);
                    aM[0][0] = __builtin_elementwise_max(aM[0][0], p0 + q0);
                    aM[0][1] = __builtin_elementwise_max(aM[0][1], p0 + q1);
                    aM[1][0] = __builtin_elementwise_max(aM[1][0], p1 + q0);
                    aM[1][1] = __builtin_elementwise_max(aM[1][1], p1 + q1);
                }
            }
        } else {
            f32x4 aU[2][2];
            #pragma unroll
            for (int jj = 0; jj < 2; jj++)
                #pragma unroll
                for (int kk = 0; kk < 2; kk++) aU[jj][kk] = NEGF;
            unsigned long long mball = __ballot(rdbool(mask, (size_t)b * 128 + wi * 64 + lane, isInt));
            for (int ch = 0; ch < 8; ch++) {
                int ibase = wi * 64 + ch * 8;
                #pragma unroll
                for (int r = 0; r < 2; r++) {
                    int f = r * 64 + lane;
                    int jr = f >> 3, ii = f & 7;
                    f32x4 pv = *(const f32x4*)(ws + E1T + (size_t)(b * 128 + j0 + jr) * 1024 + (ibase + ii) * 8 + wc * 4);
                    f32x4 qv = *(const f32x4*)(ws + E2T + (size_t)(b * 128 + k0 + jr) * 1024 + (ibase + ii) * 8 + wc * 4);
                    *(f32x4*)(Pb + jr * 36 + ii * 4) = pv;
                    *(f32x4*)(Qb + jr * 36 + ii * 4) = qv;
                }
                __builtin_amdgcn_wave_barrier();
                #pragma unroll
                for (int ii = 0; ii < 8; ii++) {
                    f32x4 p0 = *(const f32x4*)(Pb + tj * 36 + ii * 4);
                    f32x4 p1 = *(const f32x4*)(Pb + (tj + 8) * 36 + ii * 4);
                    f32x4 q0 = *(const f32x4*)(Qb + tk * 36 + ii * 4);
                    f32x4 q1 = *(const f32x4*)(Qb + (tk + 8) * 36 + ii * 4);
                    f32x4 v00 = p0 + q0, v01 = p0 + q1, v10 = p1 + q0, v11 = p1 + q1;
                    if ((mball >> (ch * 8 + ii)) & 1) {
                        aM[0][0] = __builtin_elementwise_max(aM[0][0], v00);
                        aM[0][1] = __builtin_elementwise_max(aM[0][1], v01);
                        aM[1][0] = __builtin_elementwise_max(aM[1][0], v10);
                        aM[1][1] = __builtin_elementwise_max(aM[1][1], v11);
                    } else {
                        aU[0][0] = __builtin_elementwise_max(aU[0][0], v00);
                        aU[0][1] = __builtin_elementwise_max(aU[0][1], v01);
                        aU[1][0] = __builtin_elementwise_max(aU[1][0], v10);
                        aU[1][1] = __builtin_elementwise_max(aU[1][1], v11);
                    }
                }
            }
            // outputs with mj|mk include unmasked-i contributions too
            bool mj[2], mk2[2];
            mj[0]  = (j0 + tj)     < lenb;
            mj[1]  = (j0 + tj + 8) < lenb;
            mk2[0] = (k0 + tk)     < lenb;
            mk2[1] = (k0 + tk + 8) < lenb;
            #pragma unroll
            for (int jj = 0; jj < 2; jj++)
                #pragma unroll
                for (int kk = 0; kk < 2; kk++)
                    if (mj[jj] | mk2[kk])
                        aM[jj][kk] = __builtin_elementwise_max(aM[jj][kk], aU[jj][kk]);
        }
        __syncthreads();   // all staging reads done; alias staging region as 'pooled'
        float* pooled = (float*)smem;   // [8][260] c-major
        float4 wvr[8];
        #pragma unroll
        for (int c = 0; c < 8; c++) wvr[c] = *(const float4*)(WU3 + c * 128 + col4);

        if (wi == 0) {
            #pragma unroll
            for (int jj = 0; jj < 2; jj++)
                #pragma unroll
                for (int kk = 0; kk < 2; kk++) {
                    int p = (tj + 8 * jj) * 16 + (tk + 8 * kk);
                    #pragma unroll
                    for (int cc = 0; cc < 4; cc++)
                        pooled[(wc * 4 + cc) * 260 + p] = aM[jj][kk][cc];
                }
        }
        __syncthreads();
        if (wi == 1) {
            const float* tg = ws + TRIG + (size_t)b * 8 + wc * 4;
            #pragma unroll
            for (int jj = 0; jj < 2; jj++)
                #pragma unroll
                for (int kk = 0; kk < 2; kk++) {
                    int jv = j0 + tj + 8 * jj, kv = k0 + tk + 8 * kk;
                    const float* t2 = ws + TRI2 + (size_t)(b * 128 + jv) * 8 + wc * 4;
                    const float* t3 = ws + TRI3 + (size_t)(b * 128 + kv) * 8 + wc * 4;
                    const float* e3 = ws + E3N + ((size_t)(b * 128 + jv) * 128 + kv) * 8 + wc * 4;
                    int p = (tj + 8 * jj) * 16 + (tk + 8 * kk);
                    #pragma unroll
                    for (int cc = 0; cc < 4; cc++) {
                        int idx = (wc * 4 + cc) * 260 + p;
                        pooled[idx] = fmaxf(pooled[idx], aM[jj][kk][cc]) + t2[cc] + t3[cc] + e3[cc] + tg[cc];
                    }
                }
        }
        __syncthreads();
        // epilogue: relu(pooled @ WU3); pooled reads broadcast, no LDS weights
        #pragma unroll
        for (int pass = 0; pass < 32; pass++) {
            int p = pass * 8 + rowgrp;
            float4 s = { 0.f, 0.f, 0.f, 0.f };
            #pragma unroll
            for (int c = 0; c < 8; c++) {
                float pv = pooled[c * 260 + p];
                s.x += pv * wvr[c].x; s.y += pv * wvr[c].y;
                s.z += pv * wvr[c].z; s.w += pv * wvr[c].w;
            }
            s.x = fmaxf(s.x, 0.f); s.y = fmaxf(s.y, 0.f);
            s.z = fmaxf(s.z, 0.f); s.w = fmaxf(s.w, 0.f);
            int pj = p >> 4, pk = p & 15;
            *(float4*)(out + O_TRI + ((size_t)(b * 128 + j0 + pj) * 128 + (k0 + pk)) * 128 + col4) = s;
        }
        return;
    }

    // ================= pair MLP: block = one (b,j), 32 rows/wave =================
    unsigned short* Ab = (unsigned short*)smem;                       // [128][136] 34816B
    float* pw = (float*)(smem + 34816);                               // [4][128]   2048B
    unsigned short* Wl = (unsigned short*)(smem + 36864);             // [8192]    16384B (one half-set)
    // fused final-LN scratch aliases Wl (safe: written only after the last
    // barrier that retires Wl reads; dead blocks never stage Wl)
    float* mrowL = (float*)(smem + 36864);    // [128]
    float* partL = mrowL + 128;               // [256]
    float* redL  = partL + 256;               // [4]
    int bj = bx - 256;
    int b = bj >> 7, j = bj & 127;

    int lenb;
    {
        unsigned long long m0 = __ballot(rdbool(mask, (size_t)b * 128 + lane, isInt));
        unsigned long long m1 = __ballot(rdbool(mask, (size_t)b * 128 + 64 + lane, isInt));
        lenb = __popcll(m0) + __popcll(m1);
    }
    bool live = (j < lenb);   // block-uniform

    if (live) {
        bool waveActive = (32 * w) < lenb;

        stage_h(prep, WMET_OFF, Wl, w, lane);   // Wme.h0 in flight during e-stage
        if (waveActive) {
            int half = lane >> 5, c4 = (lane & 31) * 4;
            #pragma unroll
            for (int it = 0; it < 16; it++) {
                int row = 32 * w + 2 * it + half;
                float4 v = *(const float4*)(e + (((size_t)b * 128 + row) * 128 + j) * 128 + c4);
                unsigned* dst = (unsigned*)&Ab[row * 136 + c4];
                dst[0] = pack2(v.x, v.y);
                dst[1] = pack2(v.z, v.w);
            }
        }
        __syncthreads();                        // drains vmcnt: Wme.h0 ready

        float colmax[8];
        #pragma unroll
        for (int t = 0; t < 8; t++) colmax[t] = NEGF;
        float adjm[2][4];
        f32x4 acc[2][8];

        // ---- GEMM1: X @ Wme (half-staged) ----
        #pragma unroll
        for (int rt = 0; rt < 2; rt++)
            #pragma unroll
            for (int t = 0; t < 8; t++) acc[rt][t] = 0.f;
        if (waveActive) PAIR_GEMM_H(0);
        __syncthreads();                        // done reading h0
        stage_h(prep, WMET_OFF + 8192, Wl, w, lane);
        __syncthreads();                        // h1 ready
        if (waveActive) PAIR_GEMM_H(1);
        __syncthreads();                        // done reading h1
        stage_h(prep, W1T_OFF, Wl, w, lane);    // W1.h0 hides under epilogue1

        if (waveActive) {
            float msum[8];
            #pragma unroll
            for (int t = 0; t < 8; t++)
                msum[t] = ws[MSG1 + (size_t)bj * 128 + 16 * t + n] + ws[MSGG + (size_t)b * 128 + 16 * t + n];
            float rs[2][4], rss[2][4];
            #pragma unroll
            for (int rt = 0; rt < 2; rt++)
                #pragma unroll
                for (int reg = 0; reg < 4; reg++) {
                    int row = 32 * w + 16 * rt + 4 * q + reg;
                    bool av = rdbool(adj, ((size_t)b * 128 + row) * 128 + j, isInt);
                    adjm[rt][reg] = av ? 1.f : 0.f;
                    float s = 0.f, ssq = 0.f;
                    #pragma unroll
                    for (int t = 0; t < 8; t++) {
                        float v = acc[rt][t][reg] * adjm[rt][reg]
                                + ws[MSG2 + ((size_t)b * 128 + row) * 128 + 16 * t + n] + msum[t];
                        acc[rt][t][reg] = v;
                        s += v; ssq += v * v;
                    }
                    rs[rt][reg] = s; rss[rt][reg] = ssq;
                }
            #pragma unroll
            for (int d = 1; d < 16; d <<= 1) {
                #pragma unroll
                for (int rt = 0; rt < 2; rt++)
                    #pragma unroll
                    for (int reg = 0; reg < 4; reg++) {
                        rs[rt][reg]  += __shfl_xor(rs[rt][reg], d, 64);
                        rss[rt][reg] += __shfl_xor(rss[rt][reg], d, 64);
                    }
            }
            float s1v[8], o1v[8];
            #pragma unroll
            for (int t = 0; t < 8; t++) { s1v[t] = ln1s[16 * t + n]; o1v[t] = ln1o[16 * t + n]; }
            #pragma unroll
            for (int rt = 0; rt < 2; rt++)
                #pragma unroll
                for (int reg = 0; reg < 4; reg++) {
                    float mu = rs[rt][reg] * (1.f / 128);
                    float inv = rsqrtf(rss[rt][reg] * (1.f / 128) - mu * mu + EPSF);
                    int row = 32 * w + 16 * rt + 4 * q + reg;
                    #pragma unroll
                    for (int t = 0; t < 8; t++) {
                        float v = fmaxf(s1v[t] * inv * (acc[rt][t][reg] - mu) + o1v[t], 0.f);
                        Ab[row * 136 + 16 * t + n] = f2bf(v);
                    }
                }
        }
        __syncthreads();                        // drains vmcnt: W1.h0 ready

        // ---- GEMM2: relu(LN1) @ W1 (half-staged) ----
        #pragma unroll
        for (int rt = 0; rt < 2; rt++)
            #pragma unroll
            for (int t = 0; t < 8; t++) acc[rt][t] = 0.f;
        if (waveActive) PAIR_GEMM_H(0);
        __syncthreads();
        stage_h(prep, W1T_OFF + 8192, Wl, w, lane);
        __syncthreads();
        if (waveActive) PAIR_GEMM_H(1);
        __syncthreads();
        stage_h(prep, W2T_OFF, Wl, w, lane);    // W2.h0 hides under epilogue2

        if (waveActive) {
            float rs[2][4], rss[2][4];
            #pragma unroll
            for (int rt = 0; rt < 2; rt++)
                #pragma unroll
                for (int reg = 0; reg < 4; reg++) {
                    float s = 0.f, ssq = 0.f;
                    #pragma unroll
                    for (int t = 0; t < 8; t++) { float v = acc[rt][t][reg]; s += v; ssq += v * v; }
                    rs[rt][reg] = s; rss[rt][reg] = ssq;
                }
            #pragma unroll
            for (int d = 1; d < 16; d <<= 1) {
                #pragma unroll
                for (int rt = 0; rt < 2; rt++)
                    #pragma unroll
                    for (int reg = 0; reg < 4; reg++) {
                        rs[rt][reg]  += __shfl_xor(rs[rt][reg], d, 64);
                        rss[rt][reg] += __shfl_xor(rss[rt][reg], d, 64);
                    }
            }
            float s2v[8], o2v[8];
            #pragma unroll
            for (int t = 0; t < 8; t++) { s2v[t] = ln2s[16 * t + n]; o2v[t] = ln2o[16 * t + n]; }
            #pragma unroll
            for (int rt = 0; rt < 2; rt++)
                #pragma unroll
                for (int reg = 0; reg < 4; reg++) {
                    float mu = rs[rt][reg] * (1.f / 128);
                    float inv = rsqrtf(rss[rt][reg] * (1.f / 128) - mu * mu + EPSF);
                    int row = 32 * w + 16 * rt + 4 * q + reg;
                    #pragma unroll
                    for (int t = 0; t < 8; t++) {
                        float v = fmaxf(s2v[t] * inv * (acc[rt][t][reg] - mu) + o2v[t], 0.f);
                        Ab[row * 136 + 16 * t + n] = f2bf(v);
                    }
                }
        }
        __syncthreads();                        // drains vmcnt: W2.h0 ready

        // ---- GEMM3: relu(LN2) @ W2 (half-staged) ----
        #pragma unroll
        for (int rt = 0; rt < 2; rt++)
            #pragma unroll
            for (int t = 0; t < 8; t++) acc[rt][t] = 0.f;
        if (waveActive) PAIR_GEMM_H(0);
        __syncthreads();
        stage_h(prep, W2T_OFF + 8192, Wl, w, lane);
        __syncthreads();
        if (waveActive) {
            PAIR_GEMM_H(1);
            #pragma unroll
            for (int rt = 0; rt < 2; rt++)
                #pragma unroll
                for (int reg = 0; reg < 4; reg++) {
                    if (adjm[rt][reg] > 0.f) {
                        #pragma unroll
                        for (int t = 0; t < 8; t++) colmax[t] = fmaxf(colmax[t], acc[rt][t][reg]);
                    }
                }
        }
        #pragma unroll
        for (int t = 0; t < 8; t++) {
            colmax[t] = fmaxf(colmax[t], __shfl_xor(colmax[t], 16, 64));
            colmax[t] = fmaxf(colmax[t], __shfl_xor(colmax[t], 32, 64));
        }
        if (lane < 16) {
            #pragma unroll
            for (int t = 0; t < 8; t++) pw[w * 128 + 16 * t + lane] = colmax[t];
        }
        __syncthreads();                        // last Wl reads retired; mrowL may alias now
        if (tid < 128) {
            float mx = fmaxf(fmaxf(pw[tid], pw[128 + tid]), fmaxf(pw[256 + tid], pw[384 + tid]));
            mrowL[tid] = mx;
            out[O_MSG + (size_t)bj * 128 + tid] = mx;
        }
    } else {
        // dead column: msgs row = NEGF exactly as the all-false colmax path
        if (tid < 128) {
            mrowL[tid] = NEGF;
            out[O_MSG + (size_t)bj * 128 + tid] = NEGF;
        }
    }
    __syncthreads();

    // ---- fused final LN: ret = LN(z@WU1 + msgs@WU2) ----
    {
        int c = tid & 127, hf = tid >> 7;
        int kb = hf * 64;
        float a0 = 0.f, a1 = 0.f;
        #pragma unroll 8
        for (int k = 0; k < 64; k += 2) {
            a0 = fmaf(mrowL[kb + k],     WU2[(size_t)(kb + k) * 128 + c],     a0);
            a1 = fmaf(mrowL[kb + k + 1], WU2[(size_t)(kb + k + 1) * 128 + c], a1);
        }
        partL[hf * 128 + c] = a0 + a1;
        __syncthreads();
        float y = ws[ZWU1 + (size_t)bj * 128 + c] + partL[c] + partL[128 + c];
        float s = y, ss = y * y;
        #pragma unroll
        for (int d = 1; d < 64; d <<= 1) { s += __shfl_xor(s, d, 64); ss += __shfl_xor(ss, d, 64); }
        if (tid == 0 || tid == 64) { redL[(tid >> 6) * 2] = s; redL[(tid >> 6) * 2 + 1] = ss; }
        __syncthreads();
        float S = redL[0] + redL[2], SS = redL[1] + redL[3];
        float m_ = S * (1.f / 128), v_ = SS * (1.f / 128) - m_ * m_;
        float r = rsqrtf(v_ + EPSF);
        if (tid < 128) out[O_RET + (size_t)bj * 128 + c] = lnfs[c] * r * (y - m_) + lnfo[c];
    }
}

// ============================================================
extern "C" void kernel_launch(void* const* d_in, const int* in_sizes, int n_in,
                              void* d_out, int out_size, void* d_ws, size_t ws_size,
                              hipStream_t stream)
{
    const float* z    = (const float*)d_in[0];
    const float* e    = (const float*)d_in[1];
    const float* gf   = (const float*)d_in[2];
    const void*  mask = d_in[3];
    const void*  adj  = d_in[4];
    const float* Wt1 = (const float*)d_in[5];
    const float* Wt2 = (const float*)d_in[6];
    const float* Wt3 = (const float*)d_in[7];
    const float* We1 = (const float*)d_in[8];
    const float* We2 = (const float*)d_in[9];
    const float* We3 = (const float*)d_in[10];
    const float* Wg  = (const float*)d_in[11];
    const float* Wm1 = (const float*)d_in[12];
    const float* Wm2 = (const float*)d_in[13];
    const float* Wme = (const float*)d_in[14];
    const float* Wmg = (const float*)d_in[15];
    const float* ln1s = (const float*)d_in[16];
    const float* ln1o = (const float*)d_in[17];
    const float* W1   = (const float*)d_in[18];
    const float* ln2s = (const float*)d_in[19];
    const float* ln2o = (const float*)d_in[20];
    const float* W2   = (const float*)d_in[21];
    const float* WU1  = (const float*)d_in[22];
    const float* WU2  = (const float*)d_in[23];
    const float* WU3  = (const float*)d_in[24];
    const float* lnfs = (const float*)d_in[25];
    const float* lnfo = (const float*)d_in[26];
    float* out = (float*)d_out;
    float* ws  = (float*)d_ws;
    unsigned short* prep = (unsigned short*)(ws + PREPF);

    hipLaunchKernelGGL(k_pre, dim3(1220), dim3(256), 0, stream,
                       z, e, mask, Wt1, Wt2, Wt3, Wm1, Wm2, WU1, gf, Wg, Wmg,
                       W1, W2, Wme, We1, We2, We3, ws, prep);
    hipLaunchKernelGGL(k_main, dim3(768), dim3(256), 0, stream,
                       e, mask, adj, ln1s, ln1o, ln2s, ln2o, prep, WU3,
                       WU2, lnfs, lnfo, ws, out);
}